// Round 14
// baseline (424.947 us; speedup 1.0000x reference)
//
#include <hip/hip_runtime.h>
#include <math.h>

#define N_NODES 65536
#define N_EDGES 524288
#define N_GRAPHS 1024
#define H 128
#define R_RES 512
#define NH 4
#define HD 32
#define D_IN 7
#define EPS 1e-5f

typedef __attribute__((ext_vector_type(8))) short short8;
typedef __attribute__((ext_vector_type(4))) short short4v;
typedef __attribute__((ext_vector_type(4))) float f32x4;
typedef __attribute__((ext_vector_type(4))) unsigned uint4v;
typedef __attribute__((ext_vector_type(2))) unsigned uint2v;
typedef __attribute__((ext_vector_type(4))) unsigned short us4;

#if __has_builtin(__builtin_amdgcn_exp2f)
#define EXP2F __builtin_amdgcn_exp2f
#else
#define EXP2F exp2f
#endif
#if __has_builtin(__builtin_amdgcn_rcpf)
#define RCPF __builtin_amdgcn_rcpf
#else
#define RCPF(x) (1.0f/(x))
#endif

// K=16 bf16 MFMA (v_mfma_f32_16x16x16_bf16; builtin only visible in device pass)
__device__ __forceinline__ f32x4 mfma_k16(short4v a, short4v b, f32x4 c){
#if defined(__HIP_DEVICE_COMPILE__)
  return __builtin_amdgcn_mfma_f32_16x16x16bf16_1k(a, b, c, 0, 0, 0);
#else
  (void)a; (void)b; return c;   // host pass stub, never executed
#endif
}

// round-half-up bf16 (1 add; max 0.5ulp)
__device__ __forceinline__ unsigned short rnd_bf16(float f){
  return (unsigned short)((__builtin_bit_cast(unsigned, f) + 0x8000u) >> 16);
}
// pack two floats -> bf16x2 in one v_perm
__device__ __forceinline__ unsigned pk_bf16(float lo, float hi){
  unsigned a = __builtin_bit_cast(unsigned, lo) + 0x8000u;
  unsigned b = __builtin_bit_cast(unsigned, hi) + 0x8000u;
  return __builtin_amdgcn_perm(b, a, 0x07060302u);
}
__device__ __forceinline__ float bflo(unsigned u){ return __builtin_bit_cast(float, u << 16); }
__device__ __forceinline__ float bfhi(unsigned u){ return __builtin_bit_cast(float, u & 0xFFFF0000u); }

// accumulate 8 bf16 lanes of u (4 dwords) scaled by wgt into a[8]
__device__ __forceinline__ void acc8(float* a, uint4v u, float wgt){
  a[0]=fmaf(bflo(u.x),wgt,a[0]); a[1]=fmaf(bfhi(u.x),wgt,a[1]);
  a[2]=fmaf(bflo(u.y),wgt,a[2]); a[3]=fmaf(bfhi(u.y),wgt,a[3]);
  a[4]=fmaf(bflo(u.z),wgt,a[4]); a[5]=fmaf(bfhi(u.z),wgt,a[5]);
  a[6]=fmaf(bflo(u.w),wgt,a[6]); a[7]=fmaf(bfhi(u.w),wgt,a[7]);
}

// ---------------- CSR build ----------------
__global__ __launch_bounds__(256) void k_count(const int* __restrict__ dst, int* __restrict__ cnt, int E){
  int e = blockIdx.x*256 + threadIdx.x;
  if (e < E) atomicAdd(&cnt[dst[e]], 1);
}

__global__ __launch_bounds__(256) void k_part(const int* __restrict__ cnt, int* __restrict__ part){
  int i = blockIdx.x*256 + threadIdx.x;
  int v = cnt[i];
  #pragma unroll
  for (int off=1; off<64; off<<=1) v += __shfl_xor(v, off);
  __shared__ int red[4];
  if ((threadIdx.x & 63) == 0) red[threadIdx.x >> 6] = v;
  __syncthreads();
  if (threadIdx.x == 0) part[blockIdx.x] = red[0]+red[1]+red[2]+red[3];
}

__global__ __launch_bounds__(256) void k_scanp(int* __restrict__ part){
  __shared__ int s[256];
  int t = threadIdx.x;
  int v = part[t];
  s[t] = v;
  __syncthreads();
  for (int off=1; off<256; off<<=1){
    int u = (t >= off) ? s[t-off] : 0;
    __syncthreads();
    s[t] += u;
    __syncthreads();
  }
  part[t] = s[t] - v;
}

__global__ __launch_bounds__(256) void k_apply(const int* __restrict__ cnt, const int* __restrict__ part,
      int* __restrict__ csr_off, int* __restrict__ cursor, float* __restrict__ dinv){
  __shared__ int s[256];
  int b = blockIdx.x, t = threadIdx.x;
  int i = b*256 + t;
  int c = cnt[i];
  s[t] = c;
  __syncthreads();
  for (int off=1; off<256; off<<=1){
    int u = (t >= off) ? s[t-off] : 0;
    __syncthreads();
    s[t] += u;
    __syncthreads();
  }
  int o0 = part[b] + s[t] - c;
  csr_off[i] = o0;
  cursor[i] = o0;
  dinv[i] = rsqrtf(1.0f + (float)c);
  if (i == N_NODES-1) csr_off[N_NODES] = N_EDGES;
}

// edge record = {src, weight-bits} packed in int2 -> one dwordx2 per edge in k_agg
__global__ __launch_bounds__(256) void k_fill(const int* __restrict__ src, const int* __restrict__ dst,
      const float* __restrict__ dinv, int* __restrict__ cursor, int2* __restrict__ csr_ev, int E){
  int e = blockIdx.x*256 + threadIdx.x;
  if (e >= E) return;
  int s = src[e], d = dst[e];
  int p = atomicAdd(&cursor[d], 1);
  int2 rec;
  rec.x = s;
  rec.y = __builtin_bit_cast(int, dinv[s]*dinv[d]);
  csr_ev[p] = rec;
}

// ---------------- layer-0: m = x @ W0, K=7, bf16 out ----------------
__global__ __launch_bounds__(256) void k_lin0(const float* __restrict__ x, const float* __restrict__ W0,
                                              unsigned short* __restrict__ out){
  int gid = blockIdx.x*256 + threadIdx.x;
  int l = threadIdx.x & 63;
  int n = __builtin_amdgcn_readfirstlane(gid >> 6);
  float a0 = 0.0f, a1 = 0.0f;
  #pragma unroll
  for (int k=0;k<D_IN;k++){
    float xv = x[(long)n*D_IN + k];
    float2 wv = *(const float2*)(W0 + k*H + 2*l);
    a0 = fmaf(xv, wv.x, a0); a1 = fmaf(xv, wv.y, a1);
  }
  *(unsigned*)(out + (long)n*H + 2*l) = pk_bf16(a0, a1);
}

// ---------------- bf16 MFMA GEMM: C[M,128] = A_bf16[M,128] @ B (+bias) ----------------
// outMode: 0 = bf16 row-major, 1 = fp32 row-major, 2 = bf16 transposed C^T[col*512+row]
__global__ __launch_bounds__(256) void k_gemm_mfma(const unsigned short* __restrict__ A,
      const float* __restrict__ Bsrc, const float* __restrict__ bias, void* __restrict__ Cout,
      int transB, int outMode){
  __shared__ unsigned short Bt[128][136];
  int tid = threadIdx.x;
  long rowBase = (long)blockIdx.x * 128;
  int w = tid >> 6, l = tid & 63;
  int lc = l & 15, q4 = l >> 4;

  if (transB){
    for (int i = tid; i < 4096; i += 256){
      int c = i >> 5, seg = i & 31;
      float4 v = *(const float4*)(Bsrc + (long)c*128 + seg*4);
      uint2 p; p.x = pk_bf16(v.x, v.y); p.y = pk_bf16(v.z, v.w);
      *(uint2*)&Bt[c][seg*4] = p;
    }
  } else {
    for (int i = tid; i < 4096; i += 256){
      int k = i >> 5, seg = i & 31;
      float4 v = *(const float4*)(Bsrc + (long)k*128 + seg*4);
      Bt[seg*4+0][k] = rnd_bf16(v.x); Bt[seg*4+1][k] = rnd_bf16(v.y);
      Bt[seg*4+2][k] = rnd_bf16(v.z); Bt[seg*4+3][k] = rnd_bf16(v.w);
    }
  }

  short8 af[2][4];
  #pragma unroll
  for (int rt=0;rt<2;rt++){
    long row = rowBase + w*32 + rt*16 + lc;
    #pragma unroll
    for (int kc=0;kc<4;kc++)
      af[rt][kc] = *(const short8*)(A + row*128 + kc*32 + q4*8);
  }

  f32x4 acc[2][8];
  #pragma unroll
  for (int rt=0;rt<2;rt++)
    #pragma unroll
    for (int ct=0;ct<8;ct++) acc[rt][ct] = (f32x4){0.f,0.f,0.f,0.f};

  __syncthreads();

  #pragma unroll
  for (int kc=0;kc<4;kc++){
    #pragma unroll
    for (int ct=0;ct<8;ct++){
      short8 bf = *(const short8*)&Bt[ct*16 + lc][kc*32 + q4*8];
      acc[0][ct] = __builtin_amdgcn_mfma_f32_16x16x32_bf16(af[0][kc], bf, acc[0][ct], 0,0,0);
      acc[1][ct] = __builtin_amdgcn_mfma_f32_16x16x32_bf16(af[1][kc], bf, acc[1][ct], 0,0,0);
    }
  }

  float bv[8];
  #pragma unroll
  for (int ct=0;ct<8;ct++) bv[ct] = bias ? bias[ct*16 + lc] : 0.0f;
  #pragma unroll
  for (int rt=0;rt<2;rt++){
    #pragma unroll
    for (int ct=0;ct<8;ct++){
      int col = ct*16 + lc;
      float vv[4];
      #pragma unroll
      for (int i=0;i<4;i++) vv[i] = acc[rt][ct][i] + bv[ct];
      long row0 = rowBase + w*32 + rt*16 + q4*4;
      if (outMode == 0){
        #pragma unroll
        for (int i=0;i<4;i++) ((unsigned short*)Cout)[(row0+i)*128 + col] = rnd_bf16(vv[i]);
      } else if (outMode == 1){
        #pragma unroll
        for (int i=0;i<4;i++) ((float*)Cout)[(row0+i)*128 + col] = vv[i];
      } else {
        us4 p = {rnd_bf16(vv[0]), rnd_bf16(vv[1]), rnd_bf16(vv[2]), rnd_bf16(vv[3])};
        *(us4*)((unsigned short*)Cout + (long)col*512 + row0) = p;
      }
    }
  }
}

// ---------------- repack K/V into fragment-major layouts (fused, 512 blocks) ----------------
// Layout: F[((h*32 + rc)*64 + lane)*8 + j]  (head stride 16384, chunk stride 512 shorts)
__global__ __launch_bounds__(256) void k_rp(const unsigned short* __restrict__ K,
      const unsigned short* __restrict__ Vt, unsigned short* __restrict__ FK,
      unsigned short* __restrict__ FV){
  int blk = blockIdx.x;
  int t = (blk & 255)*256 + threadIdx.x;
  if (blk < 256){
    int r = t >> 7, d = t & 127;
    int h = d >> 5, q4d = (d >> 3) & 3, j = d & 7;
    int rc = r >> 4, lc = r & 15;
    FK[(((long)(h*32 + rc)*64) + q4d*16 + lc)*8 + j] = K[t];
  } else {
    int j = t & 3, half = (t >> 2) & 1, lc = (t >> 3) & 15, q4 = (t >> 7) & 3, rc = (t >> 9) & 31, h = t >> 14;
    FV[t] = Vt[(long)(h*32 + half*16 + lc)*512 + rc*16 + q4*4 + j];
  }
}

// ---------------- GCN aggregation + bias + BN + ReLU, bf16 in/out ----------------
// Full wave per node: 4 subgroups x 16 lanes; subgroup sg walks edges e0+sg, +4, ...
// with 2-unroll (up to 8 gathers in flight/node); shfl_xor(16/32) merges partials.
__global__ __launch_bounds__(256) void k_agg(const unsigned short* __restrict__ m, const int* __restrict__ csr_off,
      const int2* __restrict__ csr_ev, const float* __restrict__ dinv,
      const float* __restrict__ b, const float* __restrict__ gamma, const float* __restrict__ beta,
      const float* __restrict__ mean, const float* __restrict__ var, unsigned short* __restrict__ out){
  int lane = threadIdx.x & 63;
  int li = lane & 15;          // col group: cols li*8 .. li*8+7
  int sg = lane >> 4;          // edge subgroup 0..3
  int n = blockIdx.x*4 + (threadIdx.x >> 6);
  int c = li*8;
  float dn = dinv[n], sn = dn*dn;
  float selfw = (sg == 0) ? sn : 0.0f;
  float a[8];
  {
    uint4v u = *(const uint4v*)(m + (long)n*H + c);
    a[0]=bflo(u.x)*selfw; a[1]=bfhi(u.x)*selfw; a[2]=bflo(u.y)*selfw; a[3]=bfhi(u.y)*selfw;
    a[4]=bflo(u.z)*selfw; a[5]=bfhi(u.z)*selfw; a[6]=bflo(u.w)*selfw; a[7]=bfhi(u.w)*selfw;
  }
  int e0 = csr_off[n], e1 = csr_off[n+1];
  int e = e0 + sg;
  for (; e + 4 < e1; e += 8){            // both e and e+4 valid
    int2 p0 = csr_ev[e], p1 = csr_ev[e+4];
    uint4v u0 = *(const uint4v*)(m + (long)p0.x*H + c);
    uint4v u1 = *(const uint4v*)(m + (long)p1.x*H + c);
    acc8(a, u0, __builtin_bit_cast(float, p0.y));
    acc8(a, u1, __builtin_bit_cast(float, p1.y));
  }
  for (; e < e1; e += 4){
    int2 p0 = csr_ev[e];
    uint4v u0 = *(const uint4v*)(m + (long)p0.x*H + c);
    acc8(a, u0, __builtin_bit_cast(float, p0.y));
  }
  // merge subgroup partials (same li across sg)
  #pragma unroll
  for (int j=0;j<8;j++){
    a[j] += __shfl_xor(a[j], 16);
    a[j] += __shfl_xor(a[j], 32);
  }
  if (sg == 0){
    float4 g0 = *(const float4*)(gamma + c), g1 = *(const float4*)(gamma + c + 4);
    float4 v0 = *(const float4*)(var   + c), v1 = *(const float4*)(var   + c + 4);
    float4 b0 = *(const float4*)(b     + c), b1 = *(const float4*)(b     + c + 4);
    float4 m0 = *(const float4*)(mean  + c), m1 = *(const float4*)(mean  + c + 4);
    float4 t0 = *(const float4*)(beta  + c), t1 = *(const float4*)(beta  + c + 4);
    float r[8];
    r[0]=fmaxf(g0.x*rsqrtf(v0.x+EPS)*(a[0]+b0.x-m0.x)+t0.x, 0.f);
    r[1]=fmaxf(g0.y*rsqrtf(v0.y+EPS)*(a[1]+b0.y-m0.y)+t0.y, 0.f);
    r[2]=fmaxf(g0.z*rsqrtf(v0.z+EPS)*(a[2]+b0.z-m0.z)+t0.z, 0.f);
    r[3]=fmaxf(g0.w*rsqrtf(v0.w+EPS)*(a[3]+b0.w-m0.w)+t0.w, 0.f);
    r[4]=fmaxf(g1.x*rsqrtf(v1.x+EPS)*(a[4]+b1.x-m1.x)+t1.x, 0.f);
    r[5]=fmaxf(g1.y*rsqrtf(v1.y+EPS)*(a[5]+b1.y-m1.y)+t1.y, 0.f);
    r[6]=fmaxf(g1.z*rsqrtf(v1.z+EPS)*(a[6]+b1.z-m1.z)+t1.z, 0.f);
    r[7]=fmaxf(g1.w*rsqrtf(v1.w+EPS)*(a[7]+b1.w-m1.w)+t1.w, 0.f);
    uint4v p;
    p.x = pk_bf16(r[0],r[1]); p.y = pk_bf16(r[2],r[3]);
    p.z = pk_bf16(r[4],r[5]); p.w = pk_bf16(r[6],r[7]);
    *(uint4v*)(out + (long)n*H + c) = p;
  }
}

// ---------------- fp32 GEMM (res projection, K=25), bf16 out ----------------
__global__ __launch_bounds__(256,2) void k_gemm(const float* __restrict__ A, const float* __restrict__ B,
      const float* __restrict__ bias, void* __restrict__ C, int K, int transB, int outBf16){
  __shared__ float Bs[128][132];
  __shared__ float As[16][128];
  int tid = threadIdx.x;
  long rowBase = (long)blockIdx.x * 128;

  if (!transB){
    for (int idx = tid; idx < 128*128; idx += 256){
      int k = idx >> 7, c = idx & 127;
      Bs[k][c] = (k < K) ? B[(long)k*128 + c] : 0.0f;
    }
  } else {
    for (int idx = tid; idx < 128*128; idx += 256){
      int c = idx >> 7, k = idx & 127;
      Bs[k][c] = (k < K) ? B[(long)c*K + k] : 0.0f;
    }
  }

  float acc[8][8];
  #pragma unroll
  for (int i=0;i<8;i++)
    #pragma unroll
    for (int j=0;j<8;j++) acc[i][j] = 0.0f;

  int rg = tid >> 4, cg = tid & 15;
  int r0 = rg*8, c0 = cg*8;
  int srow = tid >> 1, skoff = (tid & 1)*8;
  const bool fast = ((K & 15) == 0);

  for (int k0 = 0; k0 < K; k0 += 16){
    __syncthreads();
    const float* ap = A + (rowBase + srow)*K + k0 + skoff;
    if (fast){
      float4 v0 = *(const float4*)(ap);
      float4 v1 = *(const float4*)(ap + 4);
      As[skoff+0][srow] = v0.x; As[skoff+1][srow] = v0.y;
      As[skoff+2][srow] = v0.z; As[skoff+3][srow] = v0.w;
      As[skoff+4][srow] = v1.x; As[skoff+5][srow] = v1.y;
      As[skoff+6][srow] = v1.z; As[skoff+7][srow] = v1.w;
    } else {
      #pragma unroll
      for (int j=0;j<8;j++){
        int kk = k0 + skoff + j;
        As[skoff+j][srow] = (kk < K) ? ap[j] : 0.0f;
      }
    }
    __syncthreads();
    #pragma unroll
    for (int k=0;k<16;k++){
      float4 a0 = *(const float4*)(&As[k][r0]);
      float4 a1 = *(const float4*)(&As[k][r0+4]);
      float4 b0 = *(const float4*)(&Bs[k0+k][c0]);
      float4 b1 = *(const float4*)(&Bs[k0+k][c0+4]);
      float a[8] = {a0.x,a0.y,a0.z,a0.w,a1.x,a1.y,a1.z,a1.w};
      float b[8] = {b0.x,b0.y,b0.z,b0.w,b1.x,b1.y,b1.z,b1.w};
      #pragma unroll
      for (int i=0;i<8;i++)
        #pragma unroll
        for (int j=0;j<8;j++)
          acc[i][j] = fmaf(a[i], b[j], acc[i][j]);
    }
  }

  #pragma unroll
  for (int i=0;i<8;i++){
    float o[8];
    #pragma unroll
    for (int j=0;j<8;j++) o[j] = acc[i][j] + (bias ? bias[c0+j] : 0.0f);
    long row = rowBase + r0 + i;
    if (outBf16){
      uint4v p;
      p.x = pk_bf16(o[0],o[1]); p.y = pk_bf16(o[2],o[3]);
      p.z = pk_bf16(o[4],o[5]); p.w = pk_bf16(o[6],o[7]);
      *(uint4v*)((unsigned short*)C + row*128 + c0) = p;
    } else {
      float* cp = (float*)C + row*128 + c0;
      *(float4*)cp = (float4){o[0],o[1],o[2],o[3]};
      *(float4*)(cp+4) = (float4){o[4],o[5],o[6],o[7]};
    }
  }
}

// ---------------- fused q-proj + flash cross-attention, shape-mixed MFMA ----------------
// R10 config (wave = 64 nodes x 1 head, nt=4) + stage-major ordering + K/V prefetch.
__global__ __launch_bounds__(256,4) void k_attn(const unsigned short* __restrict__ hb,
      const float* __restrict__ inW, const float* __restrict__ inb,
      const unsigned short* __restrict__ Kf, const unsigned short* __restrict__ Vf,
      unsigned short* __restrict__ obuf){
  int tid = threadIdx.x;
  int h = blockIdx.y;
  int w = tid >> 6, l = tid & 63;
  int lc = l & 15, q4 = l >> 4;
  long nb = (long)blockIdx.x*256 + w*64;
  const float scale = 0.25503489f;   // log2(e)/sqrt(32)

  int srcA = lc + (q4 & 1)*32;
  int srcB = srcA + 16;
  bool hi = (q4 >> 1) != 0;

  // Wq A-frags (m=dim_local, k=hid)
  short8 wq[2][4];
  #pragma unroll
  for (int t=0;t<2;t++){
    #pragma unroll
    for (int kc=0;kc<4;kc++){
      const float* wp = inW + (long)(h*32 + t*16 + lc)*128 + kc*32 + q4*8;
      float4 x0 = *(const float4*)wp;
      float4 x1 = *(const float4*)(wp+4);
      uint4v p; p.x = pk_bf16(x0.x,x0.y); p.y = pk_bf16(x0.z,x0.w);
      p.z = pk_bf16(x1.x,x1.y); p.w = pk_bf16(x1.z,x1.w);
      wq[t][kc] = __builtin_bit_cast(short8, p);
    }
  }
  float bq0[4], bq1[4];
  #pragma unroll
  for (int i=0;i<4;i++){ bq0[i] = inb[h*32 + q4*4 + i]; bq1[i] = inb[h*32 + 16 + q4*4 + i]; }

  // q^T = Wq @ h^T per 16-node tile, C-layout -> K=32 B-frag turn (prologue only)
  short8 qB[4];
  #pragma unroll
  for (int nt=0;nt<4;nt++){
    short8 hf[4];
    #pragma unroll
    for (int kc=0;kc<4;kc++)
      hf[kc] = *(const short8*)(hb + (nb + nt*16 + lc)*128 + kc*32 + q4*8);
    f32x4 qa0 = (f32x4){0.f,0.f,0.f,0.f};
    f32x4 qa1 = (f32x4){0.f,0.f,0.f,0.f};
    #pragma unroll
    for (int kc=0;kc<4;kc++){
      qa0 = __builtin_amdgcn_mfma_f32_16x16x32_bf16(wq[0][kc], hf[kc], qa0, 0,0,0);
      qa1 = __builtin_amdgcn_mfma_f32_16x16x32_bf16(wq[1][kc], hf[kc], qa1, 0,0,0);
    }
    unsigned P0 = pk_bf16((qa0[0]+bq0[0])*scale, (qa0[1]+bq0[1])*scale);
    unsigned P1 = pk_bf16((qa0[2]+bq0[2])*scale, (qa0[3]+bq0[3])*scale);
    unsigned P2 = pk_bf16((qa1[0]+bq1[0])*scale, (qa1[1]+bq1[1])*scale);
    unsigned P3 = pk_bf16((qa1[2]+bq1[2])*scale, (qa1[3]+bq1[3])*scale);
    unsigned x0 = __shfl(P0, srcA), x1 = __shfl(P1, srcA), x2 = __shfl(P2, srcA), x3 = __shfl(P3, srcA);
    unsigned y0 = __shfl(P0, srcB), y1 = __shfl(P1, srcB), y2 = __shfl(P2, srcB), y3 = __shfl(P3, srcB);
    uint4v bp; bp.x = hi?x2:x0; bp.y = hi?x3:x1; bp.z = hi?y2:y0; bp.w = hi?y3:y1;
    qB[nt] = __builtin_bit_cast(short8, bp);
  }

  const short4v ones4 = {(short)0x3F80,(short)0x3F80,(short)0x3F80,(short)0x3F80};
  f32x4 oA[4], oB[4], os[4];
  #pragma unroll
  for (int nt=0;nt<4;nt++){
    oA[nt] = (f32x4){0.f,0.f,0.f,0.f};
    oB[nt] = (f32x4){0.f,0.f,0.f,0.f};
    os[nt] = (f32x4){0.f,0.f,0.f,0.f};
  }

  // fragment-major: head stride 16384 shorts, chunk stride 512 shorts (1KB)
  const unsigned short* Kp = Kf + (long)h*16384 + (long)l*8;
  const unsigned short* Vp = Vf + (long)h*16384 + (long)l*8;

  short8 kf = *(const short8*)(Kp);
  uint4v vv = *(const uint4v*)(Vp);
  for (int rc = 0; rc < 32; rc++){
    int rcn = (rc < 31) ? rc+1 : 31;
    short8 kfn = *(const short8*)(Kp + rcn*512);     // prefetch next chunk
    uint4v vvn = *(const uint4v*)(Vp + rcn*512);
    uint2v va = {vv.x, vv.y}, vb = {vv.z, vv.w};
    short4v vfA = __builtin_bit_cast(short4v, va);
    short4v vfB = __builtin_bit_cast(short4v, vb);
    // stage 1: all S-MFMAs back-to-back
    f32x4 s[4];
    #pragma unroll
    for (int nt=0;nt<4;nt++){
      f32x4 z = {0.f,0.f,0.f,0.f};
      s[nt] = __builtin_amdgcn_mfma_f32_16x16x32_bf16(kf, qB[nt], z, 0,0,0);
    }
    // stage 2: all exps + packs
    short4v pf[4];
    #pragma unroll
    for (int nt=0;nt<4;nt++){
      float e0 = EXP2F(s[nt][0]), e1 = EXP2F(s[nt][1]);
      float e2 = EXP2F(s[nt][2]), e3 = EXP2F(s[nt][3]);
      uint2v pk2; pk2.x = pk_bf16(e0, e1); pk2.y = pk_bf16(e2, e3);
      pf[nt] = __builtin_bit_cast(short4v, pk2);
    }
    // stage 3: all PV/denominator MFMAs
    #pragma unroll
    for (int nt=0;nt<4;nt++){
      oA[nt] = mfma_k16(vfA,   pf[nt], oA[nt]);
      oB[nt] = mfma_k16(vfB,   pf[nt], oB[nt]);
      os[nt] = mfma_k16(ones4, pf[nt], os[nt]);
    }
    kf = kfn; vv = vvn;
  }

  #pragma unroll
  for (int nt=0;nt<4;nt++){
    float inv = RCPF(os[nt][0]);
    long node = nb + nt*16 + lc;
    us4 a = { rnd_bf16(oA[nt][0]*inv), rnd_bf16(oA[nt][1]*inv),
              rnd_bf16(oA[nt][2]*inv), rnd_bf16(oA[nt][3]*inv) };
    us4 b = { rnd_bf16(oB[nt][0]*inv), rnd_bf16(oB[nt][1]*inv),
              rnd_bf16(oB[nt][2]*inv), rnd_bf16(oB[nt][3]*inv) };
    *(us4*)(obuf + node*128 + h*32 + q4*4) = a;
    *(us4*)(obuf + node*128 + h*32 + 16 + q4*4) = b;
  }
}

// ---------------- fused out-proj + mean-pool + classifier: block = 128 nodes = 2 graphs ----------------
__global__ __launch_bounds__(256) void k_gemm_out(const unsigned short* __restrict__ A,
      const float* __restrict__ Bsrc, const float* __restrict__ bias,
      const float* __restrict__ W1, const float* __restrict__ b1,
      const float* __restrict__ W2, const float* __restrict__ b2, float* __restrict__ out){
  __shared__ unsigned short Bt[128][136];
  __shared__ float pools[4][128];
  __shared__ float pooled[2][128];
  int tid = threadIdx.x;
  long rowBase = (long)blockIdx.x * 128;
  int w = tid >> 6, l = tid & 63;
  int lc = l & 15, q4 = l >> 4;

  for (int i = tid; i < 4096; i += 256){
    int c = i >> 5, seg = i & 31;
    float4 v = *(const float4*)(Bsrc + (long)c*128 + seg*4);
    uint2 p; p.x = pk_bf16(v.x, v.y); p.y = pk_bf16(v.z, v.w);
    *(uint2*)&Bt[c][seg*4] = p;
  }

  short8 af[2][4];
  #pragma unroll
  for (int rt=0;rt<2;rt++){
    long row = rowBase + w*32 + rt*16 + lc;
    #pragma unroll
    for (int kc=0;kc<4;kc++)
      af[rt][kc] = *(const short8*)(A + row*128 + kc*32 + q4*8);
  }

  f32x4 acc[2][8];
  #pragma unroll
  for (int rt=0;rt<2;rt++)
    #pragma unroll
    for (int ct=0;ct<8;ct++) acc[rt][ct] = (f32x4){0.f,0.f,0.f,0.f};

  __syncthreads();

  #pragma unroll
  for (int kc=0;kc<4;kc++){
    #pragma unroll
    for (int ct=0;ct<8;ct++){
      short8 bf = *(const short8*)&Bt[ct*16 + lc][kc*32 + q4*8];
      acc[0][ct] = __builtin_amdgcn_mfma_f32_16x16x32_bf16(af[0][kc], bf, acc[0][ct], 0,0,0);
      acc[1][ct] = __builtin_amdgcn_mfma_f32_16x16x32_bf16(af[1][kc], bf, acc[1][ct], 0,0,0);
    }
  }

  #pragma unroll
  for (int ct=0;ct<8;ct++){
    float ps = acc[0][ct][0]+acc[0][ct][1]+acc[0][ct][2]+acc[0][ct][3]
             + acc[1][ct][0]+acc[1][ct][1]+acc[1][ct][2]+acc[1][ct][3];
    ps += __shfl_xor(ps, 16);
    ps += __shfl_xor(ps, 32);
    if (q4 == 0) pools[w][ct*16 + lc] = ps;
  }
  __syncthreads();

  if (tid < 128){
    int c = tid;
    pooled[0][c] = (pools[0][c] + pools[1][c]) * (1.0f/64.0f) + bias[c];
    pooled[1][c] = (pools[2][c] + pools[3][c]) * (1.0f/64.0f) + bias[c];
  }
  __syncthreads();

  if (tid < 128){
    int g = tid >> 6, tp = tid & 63;
    float hh = b1[tp];
    for (int c=0;c<128;c++) hh = fmaf(pooled[g][c], W1[c*64 + tp], hh);
    hh = fmaxf(hh, 0.0f);
    float v = hh * W2[tp];
    #pragma unroll
    for (int off=32; off>0; off>>=1) v += __shfl_down(v, off);
    if (tp == 0) out[blockIdx.x*2 + g] = v + b2[0];
  }
}

extern "C" void kernel_launch(void* const* d_in, const int* in_sizes, int n_in,
                              void* d_out, int out_size, void* d_ws, size_t ws_size,
                              hipStream_t stream){
  const float* x     = (const float*)d_in[0];
  const int*   ei    = (const int*)d_in[1];
  const float* perres= (const float*)d_in[3];
  const float* W0 = (const float*)d_in[4];
  const float* b0 = (const float*)d_in[5];
  const float* W1 = (const float*)d_in[6];  const float* b1 = (const float*)d_in[7];
  const float* W2 = (const float*)d_in[8];  const float* b2 = (const float*)d_in[9];
  const float* bng = (const float*)d_in[10]; const float* bnb = (const float*)d_in[11];
  const float* bnm = (const float*)d_in[12]; const float* bnv = (const float*)d_in[13];
  const float* resW = (const float*)d_in[14]; const float* resb = (const float*)d_in[15];
  const float* inW  = (const float*)d_in[16]; const float* inb  = (const float*)d_in[17];
  const float* outW = (const float*)d_in[18]; const float* outb = (const float*)d_in[19];
  const float* cW1 = (const float*)d_in[20]; const float* cb1 = (const float*)d_in[21];
  const float* cW2 = (const float*)d_in[22]; const float* cb2 = (const float*)d_in[23];
  float* out = (float*)d_out;

  char* ws = (char*)d_ws;
  size_t off = 0;
  auto alloc = [&](size_t bytes) -> char* {
    char* p = ws + off;
    off += (bytes + 255) & ~(size_t)255;
    return p;
  };
  float* dinv    = (float*)alloc((size_t)N_NODES*4);
  int*   cnt     = (int*)  alloc((size_t)N_NODES*4);
  int*   cursor  = (int*)  alloc((size_t)N_NODES*4);
  int*   csr_off = (int*)  alloc((size_t)(N_NODES+1)*4);
  int2*  csr_ev  = (int2*) alloc((size_t)N_EDGES*8);
  int*   part    = (int*)  alloc((size_t)256*4);
  unsigned short* mb  = (unsigned short*)alloc((size_t)N_NODES*H*2);  // bf16: m / o
  unsigned short* hb  = (unsigned short*)alloc((size_t)N_NODES*H*2);  // bf16: h
  unsigned short* resbuf = (unsigned short*)alloc((size_t)R_RES*H*2); // bf16
  unsigned short* Kbf = (unsigned short*)alloc((size_t)R_RES*H*2);    // bf16 K [512][128]
  unsigned short* Vtb = (unsigned short*)alloc((size_t)H*R_RES*2);    // bf16 V^T [128][512]
  unsigned short* Kfr = (unsigned short*)alloc((size_t)R_RES*H*2);    // K fragment-major
  unsigned short* Vfr = (unsigned short*)alloc((size_t)H*R_RES*2);    // V fragment-major
  if (off > ws_size) return;

  const int* srcI = ei;
  const int* dstI = ei + N_EDGES;

  // CSR build (parallel 3-phase scan)
  (void)hipMemsetAsync(cnt, 0, (size_t)N_NODES*4, stream);
  k_count<<<N_EDGES/256, 256, 0, stream>>>(dstI, cnt, N_EDGES);
  k_part <<<N_NODES/256, 256, 0, stream>>>(cnt, part);
  k_scanp<<<1, 256, 0, stream>>>(part);
  k_apply<<<N_NODES/256, 256, 0, stream>>>(cnt, part, csr_off, cursor, dinv);
  k_fill <<<N_EDGES/256, 256, 0, stream>>>(srcI, dstI, dinv, cursor, csr_ev, N_EDGES);

  const int NB = N_NODES/128;
  const int AGB = N_NODES/4;    // 4 nodes (4 waves) per 256-thread block
  // GCN: layer 0 (K=7 VALU), layers 1/2 via MFMA
  k_lin0<<<N_NODES/4, 256, 0, stream>>>(x, W0, mb);
  k_agg<<<AGB, 256, 0, stream>>>(mb, csr_off, csr_ev, dinv, b0, bng,     bnb,     bnm,     bnv,     hb);
  k_gemm_mfma<<<NB, 256, 0, stream>>>(hb, W1, nullptr, mb, 0, 0);
  k_agg<<<AGB, 256, 0, stream>>>(mb, csr_off, csr_ev, dinv, b1, bng+128, bnb+128, bnm+128, bnv+128, hb);
  k_gemm_mfma<<<NB, 256, 0, stream>>>(hb, W2, nullptr, mb, 0, 0);
  k_agg<<<AGB, 256, 0, stream>>>(mb, csr_off, csr_ev, dinv, b2, bng+256, bnb+256, bnm+256, bnv+256, hb);

  // residue chain: res-proj -> K (row-major) / V (transposed) -> fragment-major repack (fused)
  k_gemm<<<R_RES/128, 256, 0, stream>>>(perres, resW, resb, resbuf, 25, 0, 1);
  k_gemm_mfma<<<R_RES/128, 256, 0, stream>>>(resbuf, inW + 128*128, inb + 128, Kbf, 1, 0);
  k_gemm_mfma<<<R_RES/128, 256, 0, stream>>>(resbuf, inW + 256*128, inb + 256, Vtb, 1, 2);
  k_rp<<<512, 256, 0, stream>>>(Kbf, Vtb, Kfr, Vfr);

  // fused q-proj + attention (o -> mb)
  dim3 agrid(N_NODES/256, NH);
  k_attn<<<agrid, 256, 0, stream>>>(hb, inW, inb, Kfr, Vfr, mb);

  // fused out-proj + mean pool + classifier
  k_gemm_out<<<NB, 256, 0, stream>>>(mb, outW, outb, cW1, cb1, cW2, cb2, out);
}

// Round 15
// 375.750 us; speedup vs baseline: 1.1309x; 1.1309x over previous
//
#include <hip/hip_runtime.h>
#include <math.h>

#define N_NODES 65536
#define N_EDGES 524288
#define N_GRAPHS 1024
#define H 128
#define R_RES 512
#define NH 4
#define HD 32
#define D_IN 7
#define EPS 1e-5f

typedef __attribute__((ext_vector_type(8))) short short8;
typedef __attribute__((ext_vector_type(4))) short short4v;
typedef __attribute__((ext_vector_type(4))) float f32x4;
typedef __attribute__((ext_vector_type(4))) unsigned uint4v;
typedef __attribute__((ext_vector_type(2))) unsigned uint2v;
typedef __attribute__((ext_vector_type(4))) unsigned short us4;

#if __has_builtin(__builtin_amdgcn_exp2f)
#define EXP2F __builtin_amdgcn_exp2f
#else
#define EXP2F exp2f
#endif
#if __has_builtin(__builtin_amdgcn_rcpf)
#define RCPF __builtin_amdgcn_rcpf
#else
#define RCPF(x) (1.0f/(x))
#endif

// K=16 bf16 MFMA (v_mfma_f32_16x16x16_bf16; builtin only visible in device pass)
__device__ __forceinline__ f32x4 mfma_k16(short4v a, short4v b, f32x4 c){
#if defined(__HIP_DEVICE_COMPILE__)
  return __builtin_amdgcn_mfma_f32_16x16x16bf16_1k(a, b, c, 0, 0, 0);
#else
  (void)a; (void)b; return c;   // host pass stub, never executed
#endif
}

// round-half-up bf16 (1 add; max 0.5ulp)
__device__ __forceinline__ unsigned short rnd_bf16(float f){
  return (unsigned short)((__builtin_bit_cast(unsigned, f) + 0x8000u) >> 16);
}
// pack two floats -> bf16x2 in one v_perm
__device__ __forceinline__ unsigned pk_bf16(float lo, float hi){
  unsigned a = __builtin_bit_cast(unsigned, lo) + 0x8000u;
  unsigned b = __builtin_bit_cast(unsigned, hi) + 0x8000u;
  return __builtin_amdgcn_perm(b, a, 0x07060302u);
}
__device__ __forceinline__ float bflo(unsigned u){ return __builtin_bit_cast(float, u << 16); }
__device__ __forceinline__ float bfhi(unsigned u){ return __builtin_bit_cast(float, u & 0xFFFF0000u); }

// accumulate 8 bf16 lanes of u (4 dwords) scaled by wgt into a[8]
__device__ __forceinline__ void acc8(float* a, uint4v u, float wgt){
  a[0]=fmaf(bflo(u.x),wgt,a[0]); a[1]=fmaf(bfhi(u.x),wgt,a[1]);
  a[2]=fmaf(bflo(u.y),wgt,a[2]); a[3]=fmaf(bfhi(u.y),wgt,a[3]);
  a[4]=fmaf(bflo(u.z),wgt,a[4]); a[5]=fmaf(bfhi(u.z),wgt,a[5]);
  a[6]=fmaf(bflo(u.w),wgt,a[6]); a[7]=fmaf(bfhi(u.w),wgt,a[7]);
}

// ---------------- CSR build ----------------
__global__ __launch_bounds__(256) void k_count(const int* __restrict__ dst, int* __restrict__ cnt, int E){
  int e = blockIdx.x*256 + threadIdx.x;
  if (e < E) atomicAdd(&cnt[dst[e]], 1);
}

__global__ __launch_bounds__(256) void k_part(const int* __restrict__ cnt, int* __restrict__ part){
  int i = blockIdx.x*256 + threadIdx.x;
  int v = cnt[i];
  #pragma unroll
  for (int off=1; off<64; off<<=1) v += __shfl_xor(v, off);
  __shared__ int red[4];
  if ((threadIdx.x & 63) == 0) red[threadIdx.x >> 6] = v;
  __syncthreads();
  if (threadIdx.x == 0) part[blockIdx.x] = red[0]+red[1]+red[2]+red[3];
}

__global__ __launch_bounds__(256) void k_scanp(int* __restrict__ part){
  __shared__ int s[256];
  int t = threadIdx.x;
  int v = part[t];
  s[t] = v;
  __syncthreads();
  for (int off=1; off<256; off<<=1){
    int u = (t >= off) ? s[t-off] : 0;
    __syncthreads();
    s[t] += u;
    __syncthreads();
  }
  part[t] = s[t] - v;
}

__global__ __launch_bounds__(256) void k_apply(const int* __restrict__ cnt, const int* __restrict__ part,
      int* __restrict__ csr_off, int* __restrict__ cursor, float* __restrict__ dinv){
  __shared__ int s[256];
  int b = blockIdx.x, t = threadIdx.x;
  int i = b*256 + t;
  int c = cnt[i];
  s[t] = c;
  __syncthreads();
  for (int off=1; off<256; off<<=1){
    int u = (t >= off) ? s[t-off] : 0;
    __syncthreads();
    s[t] += u;
    __syncthreads();
  }
  int o0 = part[b] + s[t] - c;
  csr_off[i] = o0;
  cursor[i] = o0;
  dinv[i] = rsqrtf(1.0f + (float)c);
  if (i == N_NODES-1) csr_off[N_NODES] = N_EDGES;
}

// edge record = {src, weight-bits} packed in int2 -> one dwordx2 per edge in k_agg
__global__ __launch_bounds__(256) void k_fill(const int* __restrict__ src, const int* __restrict__ dst,
      const float* __restrict__ dinv, int* __restrict__ cursor, int2* __restrict__ csr_ev, int E){
  int e = blockIdx.x*256 + threadIdx.x;
  if (e >= E) return;
  int s = src[e], d = dst[e];
  int p = atomicAdd(&cursor[d], 1);
  int2 rec;
  rec.x = s;
  rec.y = __builtin_bit_cast(int, dinv[s]*dinv[d]);
  csr_ev[p] = rec;
}

// ---------------- layer-0: m = x @ W0, K=7, bf16 out ----------------
__global__ __launch_bounds__(256) void k_lin0(const float* __restrict__ x, const float* __restrict__ W0,
                                              unsigned short* __restrict__ out){
  int gid = blockIdx.x*256 + threadIdx.x;
  int l = threadIdx.x & 63;
  int n = __builtin_amdgcn_readfirstlane(gid >> 6);
  float a0 = 0.0f, a1 = 0.0f;
  #pragma unroll
  for (int k=0;k<D_IN;k++){
    float xv = x[(long)n*D_IN + k];
    float2 wv = *(const float2*)(W0 + k*H + 2*l);
    a0 = fmaf(xv, wv.x, a0); a1 = fmaf(xv, wv.y, a1);
  }
  *(unsigned*)(out + (long)n*H + 2*l) = pk_bf16(a0, a1);
}

// ---------------- bf16 MFMA GEMM: C[M,128] = A_bf16[M,128] @ B (+bias) ----------------
// outMode: 0 = bf16 row-major, 1 = fp32 row-major
__global__ __launch_bounds__(256) void k_gemm_mfma(const unsigned short* __restrict__ A,
      const float* __restrict__ Bsrc, const float* __restrict__ bias, void* __restrict__ Cout,
      int transB, int outMode){
  __shared__ unsigned short Bt[128][136];
  int tid = threadIdx.x;
  long rowBase = (long)blockIdx.x * 128;
  int w = tid >> 6, l = tid & 63;
  int lc = l & 15, q4 = l >> 4;

  if (transB){
    for (int i = tid; i < 4096; i += 256){
      int c = i >> 5, seg = i & 31;
      float4 v = *(const float4*)(Bsrc + (long)c*128 + seg*4);
      uint2 p; p.x = pk_bf16(v.x, v.y); p.y = pk_bf16(v.z, v.w);
      *(uint2*)&Bt[c][seg*4] = p;
    }
  } else {
    for (int i = tid; i < 4096; i += 256){
      int k = i >> 5, seg = i & 31;
      float4 v = *(const float4*)(Bsrc + (long)k*128 + seg*4);
      Bt[seg*4+0][k] = rnd_bf16(v.x); Bt[seg*4+1][k] = rnd_bf16(v.y);
      Bt[seg*4+2][k] = rnd_bf16(v.z); Bt[seg*4+3][k] = rnd_bf16(v.w);
    }
  }

  short8 af[2][4];
  #pragma unroll
  for (int rt=0;rt<2;rt++){
    long row = rowBase + w*32 + rt*16 + lc;
    #pragma unroll
    for (int kc=0;kc<4;kc++)
      af[rt][kc] = *(const short8*)(A + row*128 + kc*32 + q4*8);
  }

  f32x4 acc[2][8];
  #pragma unroll
  for (int rt=0;rt<2;rt++)
    #pragma unroll
    for (int ct=0;ct<8;ct++) acc[rt][ct] = (f32x4){0.f,0.f,0.f,0.f};

  __syncthreads();

  #pragma unroll
  for (int kc=0;kc<4;kc++){
    #pragma unroll
    for (int ct=0;ct<8;ct++){
      short8 bf = *(const short8*)&Bt[ct*16 + lc][kc*32 + q4*8];
      acc[0][ct] = __builtin_amdgcn_mfma_f32_16x16x32_bf16(af[0][kc], bf, acc[0][ct], 0,0,0);
      acc[1][ct] = __builtin_amdgcn_mfma_f32_16x16x32_bf16(af[1][kc], bf, acc[1][ct], 0,0,0);
    }
  }

  float bv[8];
  #pragma unroll
  for (int ct=0;ct<8;ct++) bv[ct] = bias ? bias[ct*16 + lc] : 0.0f;
  #pragma unroll
  for (int rt=0;rt<2;rt++){
    #pragma unroll
    for (int ct=0;ct<8;ct++){
      int col = ct*16 + lc;
      float vv[4];
      #pragma unroll
      for (int i=0;i<4;i++) vv[i] = acc[rt][ct][i] + bv[ct];
      long row0 = rowBase + w*32 + rt*16 + q4*4;
      if (outMode == 0){
        #pragma unroll
        for (int i=0;i<4;i++) ((unsigned short*)Cout)[(row0+i)*128 + col] = rnd_bf16(vv[i]);
      } else {
        #pragma unroll
        for (int i=0;i<4;i++) ((float*)Cout)[(row0+i)*128 + col] = vv[i];
      }
    }
  }
}

// ---------------- fused K+V projection GEMM, writing fragment-major directly ----------------
// Grid = 8 blocks: b<4 -> K rows b*128.., b>=4 -> V rows (b-4)*128..
// Frag layout: F[h*16384 + rc*512 + lane*8 + j] (head stride 16384, chunk stride 512 shorts).
__global__ __launch_bounds__(256) void k_kv(const unsigned short* __restrict__ A,
      const float* __restrict__ inW, const float* __restrict__ inb,
      unsigned short* __restrict__ FK, unsigned short* __restrict__ FV){
  __shared__ unsigned short Bt[128][136];
  int tid = threadIdx.x;
  int blk = blockIdx.x;
  int isK = (blk < 4);
  const float* Bsrc = inW + (isK ? 128*128 : 256*128);
  const float* bias = inb + (isK ? 128 : 256);
  long rowBase = (long)(blk & 3) * 128;
  int w = tid >> 6, l = tid & 63;
  int lc = l & 15, q4 = l >> 4;

  for (int i = tid; i < 4096; i += 256){    // B = W^T: B(k,c) = Bsrc[c*128+k]
    int c = i >> 5, seg = i & 31;
    float4 v = *(const float4*)(Bsrc + (long)c*128 + seg*4);
    uint2 p; p.x = pk_bf16(v.x, v.y); p.y = pk_bf16(v.z, v.w);
    *(uint2*)&Bt[c][seg*4] = p;
  }

  short8 af[2][4];
  #pragma unroll
  for (int rt=0;rt<2;rt++){
    long row = rowBase + w*32 + rt*16 + lc;
    #pragma unroll
    for (int kc=0;kc<4;kc++)
      af[rt][kc] = *(const short8*)(A + row*128 + kc*32 + q4*8);
  }

  f32x4 acc[2][8];
  #pragma unroll
  for (int rt=0;rt<2;rt++)
    #pragma unroll
    for (int ct=0;ct<8;ct++) acc[rt][ct] = (f32x4){0.f,0.f,0.f,0.f};

  __syncthreads();

  #pragma unroll
  for (int kc=0;kc<4;kc++){
    #pragma unroll
    for (int ct=0;ct<8;ct++){
      short8 bf = *(const short8*)&Bt[ct*16 + lc][kc*32 + q4*8];
      acc[0][ct] = __builtin_amdgcn_mfma_f32_16x16x32_bf16(af[0][kc], bf, acc[0][ct], 0,0,0);
      acc[1][ct] = __builtin_amdgcn_mfma_f32_16x16x32_bf16(af[1][kc], bf, acc[1][ct], 0,0,0);
    }
  }

  float bv[8];
  #pragma unroll
  for (int ct=0;ct<8;ct++) bv[ct] = bias[ct*16 + lc];
  #pragma unroll
  for (int rt=0;rt<2;rt++){
    long rc = ((blk & 3)*128 + w*32 + rt*16) >> 4;    // res-chunk index (0..31)
    #pragma unroll
    for (int ct=0;ct<8;ct++){
      float vv[4];
      #pragma unroll
      for (int i=0;i<4;i++) vv[i] = acc[rt][ct][i] + bv[ct];
      int h = ct >> 1;
      if (isK){
        // element (r=row0+i, d=ct*16+lc): lcK=q4*4+i, q4d=((ct*16+lc)>>3)&3, j=lc&7
        int q4d = (ct*2 + (lc >> 3)) & 3;
        long base = (long)h*16384 + rc*512 + q4d*128 + (q4*4)*8 + (lc & 7);
        #pragma unroll
        for (int i=0;i<4;i++) FK[base + i*8] = rnd_bf16(vv[i]);
      } else {
        // V-frag: contiguous us4 at h*16384 + rc*512 + q4*128 + lc*8 + (ct&1)*4, j=i
        long base = (long)h*16384 + rc*512 + q4*128 + lc*8 + (ct & 1)*4;
        us4 p = { rnd_bf16(vv[0]), rnd_bf16(vv[1]), rnd_bf16(vv[2]), rnd_bf16(vv[3]) };
        *(us4*)(FV + base) = p;
      }
    }
  }
}

// ---------------- GCN aggregation + bias + BN + ReLU, bf16 in/out ----------------
// 16 lanes per node (8 cols/lane, dwordx4 gathers), 4 nodes/wave, 4-edge unroll. (R13 config)
__global__ __launch_bounds__(256) void k_agg(const unsigned short* __restrict__ m, const int* __restrict__ csr_off,
      const int2* __restrict__ csr_ev, const float* __restrict__ dinv,
      const float* __restrict__ b, const float* __restrict__ gamma, const float* __restrict__ beta,
      const float* __restrict__ mean, const float* __restrict__ var, unsigned short* __restrict__ out){
  int gt = blockIdx.x*256 + threadIdx.x;
  int li = gt & 15;
  int n = gt >> 4;
  int c = li*8;
  float dn = dinv[n], sn = dn*dn;
  float a[8];
  {
    uint4v u = *(const uint4v*)(m + (long)n*H + c);
    a[0]=bflo(u.x)*sn; a[1]=bfhi(u.x)*sn; a[2]=bflo(u.y)*sn; a[3]=bfhi(u.y)*sn;
    a[4]=bflo(u.z)*sn; a[5]=bfhi(u.z)*sn; a[6]=bflo(u.w)*sn; a[7]=bfhi(u.w)*sn;
  }
  int e0 = csr_off[n], e1 = csr_off[n+1];
  int e = e0;
  for (; e + 4 <= e1; e += 4){
    int2 p0 = csr_ev[e],   p1 = csr_ev[e+1];
    int2 p2 = csr_ev[e+2], p3 = csr_ev[e+3];
    uint4v u0 = *(const uint4v*)(m + (long)p0.x*H + c);
    uint4v u1 = *(const uint4v*)(m + (long)p1.x*H + c);
    uint4v u2 = *(const uint4v*)(m + (long)p2.x*H + c);
    uint4v u3 = *(const uint4v*)(m + (long)p3.x*H + c);
    acc8(a, u0, __builtin_bit_cast(float, p0.y));
    acc8(a, u1, __builtin_bit_cast(float, p1.y));
    acc8(a, u2, __builtin_bit_cast(float, p2.y));
    acc8(a, u3, __builtin_bit_cast(float, p3.y));
  }
  for (; e < e1; e++){
    int2 p0 = csr_ev[e];
    uint4v u0 = *(const uint4v*)(m + (long)p0.x*H + c);
    acc8(a, u0, __builtin_bit_cast(float, p0.y));
  }
  float4 g0 = *(const float4*)(gamma + c), g1 = *(const float4*)(gamma + c + 4);
  float4 v0 = *(const float4*)(var   + c), v1 = *(const float4*)(var   + c + 4);
  float4 b0 = *(const float4*)(b     + c), b1 = *(const float4*)(b     + c + 4);
  float4 m0 = *(const float4*)(mean  + c), m1 = *(const float4*)(mean  + c + 4);
  float4 t0 = *(const float4*)(beta  + c), t1 = *(const float4*)(beta  + c + 4);
  float r[8];
  r[0]=fmaxf(g0.x*rsqrtf(v0.x+EPS)*(a[0]+b0.x-m0.x)+t0.x, 0.f);
  r[1]=fmaxf(g0.y*rsqrtf(v0.y+EPS)*(a[1]+b0.y-m0.y)+t0.y, 0.f);
  r[2]=fmaxf(g0.z*rsqrtf(v0.z+EPS)*(a[2]+b0.z-m0.z)+t0.z, 0.f);
  r[3]=fmaxf(g0.w*rsqrtf(v0.w+EPS)*(a[3]+b0.w-m0.w)+t0.w, 0.f);
  r[4]=fmaxf(g1.x*rsqrtf(v1.x+EPS)*(a[4]+b1.x-m1.x)+t1.x, 0.f);
  r[5]=fmaxf(g1.y*rsqrtf(v1.y+EPS)*(a[5]+b1.y-m1.y)+t1.y, 0.f);
  r[6]=fmaxf(g1.z*rsqrtf(v1.z+EPS)*(a[6]+b1.z-m1.z)+t1.z, 0.f);
  r[7]=fmaxf(g1.w*rsqrtf(v1.w+EPS)*(a[7]+b1.w-m1.w)+t1.w, 0.f);
  uint4v p;
  p.x = pk_bf16(r[0],r[1]); p.y = pk_bf16(r[2],r[3]);
  p.z = pk_bf16(r[4],r[5]); p.w = pk_bf16(r[6],r[7]);
  *(uint4v*)(out + (long)n*H + c) = p;
}

// ---------------- fp32 GEMM (res projection, K=25), bf16 out ----------------
__global__ __launch_bounds__(256,2) void k_gemm(const float* __restrict__ A, const float* __restrict__ B,
      const float* __restrict__ bias, void* __restrict__ C, int K, int transB, int outBf16){
  __shared__ float Bs[128][132];
  __shared__ float As[16][128];
  int tid = threadIdx.x;
  long rowBase = (long)blockIdx.x * 128;

  if (!transB){
    for (int idx = tid; idx < 128*128; idx += 256){
      int k = idx >> 7, c = idx & 127;
      Bs[k][c] = (k < K) ? B[(long)k*128 + c] : 0.0f;
    }
  } else {
    for (int idx = tid; idx < 128*128; idx += 256){
      int c = idx >> 7, k = idx & 127;
      Bs[k][c] = (k < K) ? B[(long)c*K + k] : 0.0f;
    }
  }

  float acc[8][8];
  #pragma unroll
  for (int i=0;i<8;i++)
    #pragma unroll
    for (int j=0;j<8;j++) acc[i][j] = 0.0f;

  int rg = tid >> 4, cg = tid & 15;
  int r0 = rg*8, c0 = cg*8;
  int srow = tid >> 1, skoff = (tid & 1)*8;
  const bool fast = ((K & 15) == 0);

  for (int k0 = 0; k0 < K; k0 += 16){
    __syncthreads();
    const float* ap = A + (rowBase + srow)*K + k0 + skoff;
    if (fast){
      float4 v0 = *(const float4*)(ap);
      float4 v1 = *(const float4*)(ap + 4);
      As[skoff+0][srow] = v0.x; As[skoff+1][srow] = v0.y;
      As[skoff+2][srow] = v0.z; As[skoff+3][srow] = v0.w;
      As[skoff+4][srow] = v1.x; As[skoff+5][srow] = v1.y;
      As[skoff+6][srow] = v1.z; As[skoff+7][srow] = v1.w;
    } else {
      #pragma unroll
      for (int j=0;j<8;j++){
        int kk = k0 + skoff + j;
        As[skoff+j][srow] = (kk < K) ? ap[j] : 0.0f;
      }
    }
    __syncthreads();
    #pragma unroll
    for (int k=0;k<16;k++){
      float4 a0 = *(const float4*)(&As[k][r0]);
      float4 a1 = *(const float4*)(&As[k][r0+4]);
      float4 b0 = *(const float4*)(&Bs[k0+k][c0]);
      float4 b1 = *(const float4*)(&Bs[k0+k][c0+4]);
      float a[8] = {a0.x,a0.y,a0.z,a0.w,a1.x,a1.y,a1.z,a1.w};
      float b[8] = {b0.x,b0.y,b0.z,b0.w,b1.x,b1.y,b1.z,b1.w};
      #pragma unroll
      for (int i=0;i<8;i++)
        #pragma unroll
        for (int j=0;j<8;j++)
          acc[i][j] = fmaf(a[i], b[j], acc[i][j]);
    }
  }

  #pragma unroll
  for (int i=0;i<8;i++){
    float o[8];
    #pragma unroll
    for (int j=0;j<8;j++) o[j] = acc[i][j] + (bias ? bias[c0+j] : 0.0f);
    long row = rowBase + r0 + i;
    if (outBf16){
      uint4v p;
      p.x = pk_bf16(o[0],o[1]); p.y = pk_bf16(o[2],o[3]);
      p.z = pk_bf16(o[4],o[5]); p.w = pk_bf16(o[6],o[7]);
      *(uint4v*)((unsigned short*)C + row*128 + c0) = p;
    } else {
      float* cp = (float*)C + row*128 + c0;
      *(float4*)cp = (float4){o[0],o[1],o[2],o[3]};
      *(float4*)(cp+4) = (float4){o[4],o[5],o[6],o[7]};
    }
  }
}

// ---------------- fused q-proj + flash cross-attention, shape-mixed MFMA (R13 config) ----------------
__global__ __launch_bounds__(256,4) void k_attn(const unsigned short* __restrict__ hb,
      const float* __restrict__ inW, const float* __restrict__ inb,
      const unsigned short* __restrict__ Kf, const unsigned short* __restrict__ Vf,
      unsigned short* __restrict__ obuf){
  int tid = threadIdx.x;
  int h = blockIdx.y;
  int w = tid >> 6, l = tid & 63;
  int lc = l & 15, q4 = l >> 4;
  long nb = (long)blockIdx.x*256 + w*64;
  const float scale = 0.25503489f;   // log2(e)/sqrt(32)

  int srcA = lc + (q4 & 1)*32;
  int srcB = srcA + 16;
  bool hi = (q4 >> 1) != 0;

  // Wq A-frags (m=dim_local, k=hid)
  short8 wq[2][4];
  #pragma unroll
  for (int t=0;t<2;t++){
    #pragma unroll
    for (int kc=0;kc<4;kc++){
      const float* wp = inW + (long)(h*32 + t*16 + lc)*128 + kc*32 + q4*8;
      float4 x0 = *(const float4*)wp;
      float4 x1 = *(const float4*)(wp+4);
      uint4v p; p.x = pk_bf16(x0.x,x0.y); p.y = pk_bf16(x0.z,x0.w);
      p.z = pk_bf16(x1.x,x1.y); p.w = pk_bf16(x1.z,x1.w);
      wq[t][kc] = __builtin_bit_cast(short8, p);
    }
  }
  float bq0[4], bq1[4];
  #pragma unroll
  for (int i=0;i<4;i++){ bq0[i] = inb[h*32 + q4*4 + i]; bq1[i] = inb[h*32 + 16 + q4*4 + i]; }

  // q^T = Wq @ h^T per 16-node tile, C-layout -> K=32 B-frag turn (prologue only)
  short8 qB[4];
  #pragma unroll
  for (int nt=0;nt<4;nt++){
    short8 hf[4];
    #pragma unroll
    for (int kc=0;kc<4;kc++)
      hf[kc] = *(const short8*)(hb + (nb + nt*16 + lc)*128 + kc*32 + q4*8);
    f32x4 qa0 = (f32x4){0.f,0.f,0.f,0.f};
    f32x4 qa1 = (f32x4){0.f,0.f,0.f,0.f};
    #pragma unroll
    for (int kc=0;kc<4;kc++){
      qa0 = __builtin_amdgcn_mfma_f32_16x16x32_bf16(wq[0][kc], hf[kc], qa0, 0,0,0);
      qa1 = __builtin_amdgcn_mfma_f32_16x16x32_bf16(wq[1][kc], hf[kc], qa1, 0,0,0);
    }
    unsigned P0 = pk_bf16((qa0[0]+bq0[0])*scale, (qa0[1]+bq0[1])*scale);
    unsigned P1 = pk_bf16((qa0[2]+bq0[2])*scale, (qa0[3]+bq0[3])*scale);
    unsigned P2 = pk_bf16((qa1[0]+bq1[0])*scale, (qa1[1]+bq1[1])*scale);
    unsigned P3 = pk_bf16((qa1[2]+bq1[2])*scale, (qa1[3]+bq1[3])*scale);
    unsigned x0 = __shfl(P0, srcA), x1 = __shfl(P1, srcA), x2 = __shfl(P2, srcA), x3 = __shfl(P3, srcA);
    unsigned y0 = __shfl(P0, srcB), y1 = __shfl(P1, srcB), y2 = __shfl(P2, srcB), y3 = __shfl(P3, srcB);
    uint4v bp; bp.x = hi?x2:x0; bp.y = hi?x3:x1; bp.z = hi?y2:y0; bp.w = hi?y3:y1;
    qB[nt] = __builtin_bit_cast(short8, bp);
  }

  const short4v ones4 = {(short)0x3F80,(short)0x3F80,(short)0x3F80,(short)0x3F80};
  f32x4 oA[4], oB[4], os[4];
  #pragma unroll
  for (int nt=0;nt<4;nt++){
    oA[nt] = (f32x4){0.f,0.f,0.f,0.f};
    oB[nt] = (f32x4){0.f,0.f,0.f,0.f};
    os[nt] = (f32x4){0.f,0.f,0.f,0.f};
  }

  // fragment-major: head stride 16384 shorts, chunk stride 512 shorts (1KB)
  const unsigned short* Kp = Kf + (long)h*16384 + (long)l*8;
  const unsigned short* Vp = Vf + (long)h*16384 + (long)l*8;

  for (int rc = 0; rc < 32; rc++){
    short8 kf = *(const short8*)(Kp + rc*512);            // coalesced 1KB
    uint4v vv = *(const uint4v*)(Vp + rc*512);            // coalesced 1KB: [vfA|vfB]
    uint2v va = {vv.x, vv.y}, vb = {vv.z, vv.w};
    short4v vfA = __builtin_bit_cast(short4v, va);
    short4v vfB = __builtin_bit_cast(short4v, vb);
    #pragma unroll
    for (int nt=0;nt<4;nt++){
      f32x4 z = {0.f,0.f,0.f,0.f};
      f32x4 s = __builtin_amdgcn_mfma_f32_16x16x32_bf16(kf, qB[nt], z, 0,0,0);
      float e0 = EXP2F(s[0]), e1 = EXP2F(s[1]), e2 = EXP2F(s[2]), e3 = EXP2F(s[3]);
      uint2v pk2; pk2.x = pk_bf16(e0, e1); pk2.y = pk_bf16(e2, e3);
      short4v pf = __builtin_bit_cast(short4v, pk2);      // P^T B-frag, directly
      oA[nt] = mfma_k16(vfA,   pf, oA[nt]);
      oB[nt] = mfma_k16(vfB,   pf, oB[nt]);
      os[nt] = mfma_k16(ones4, pf, os[nt]);               // softmax denominators
    }
  }

  #pragma unroll
  for (int nt=0;nt<4;nt++){
    float inv = RCPF(os[nt][0]);
    long node = nb + nt*16 + lc;
    us4 a = { rnd_bf16(oA[nt][0]*inv), rnd_bf16(oA[nt][1]*inv),
              rnd_bf16(oA[nt][2]*inv), rnd_bf16(oA[nt][3]*inv) };
    us4 b = { rnd_bf16(oB[nt][0]*inv), rnd_bf16(oB[nt][1]*inv),
              rnd_bf16(oB[nt][2]*inv), rnd_bf16(oB[nt][3]*inv) };
    *(us4*)(obuf + node*128 + h*32 + q4*4) = a;
    *(us4*)(obuf + node*128 + h*32 + 16 + q4*4) = b;
  }
}

// ---------------- fused out-proj + mean-pool + classifier: block = 128 nodes = 2 graphs ----------------
__global__ __launch_bounds__(256) void k_gemm_out(const unsigned short* __restrict__ A,
      const float* __restrict__ Bsrc, const float* __restrict__ bias,
      const float* __restrict__ W1, const float* __restrict__ b1,
      const float* __restrict__ W2, const float* __restrict__ b2, float* __restrict__ out){
  __shared__ unsigned short Bt[128][136];
  __shared__ float pools[4][128];
  __shared__ float pooled[2][128];
  int tid = threadIdx.x;
  long rowBase = (long)blockIdx.x * 128;
  int w = tid >> 6, l = tid & 63;
  int lc = l & 15, q4 = l >> 4;

  for (int i = tid; i < 4096; i += 256){
    int c = i >> 5, seg = i & 31;
    float4 v = *(const float4*)(Bsrc + (long)c*128 + seg*4);
    uint2 p; p.x = pk_bf16(v.x, v.y); p.y = pk_bf16(v.z, v.w);
    *(uint2*)&Bt[c][seg*4] = p;
  }

  short8 af[2][4];
  #pragma unroll
  for (int rt=0;rt<2;rt++){
    long row = rowBase + w*32 + rt*16 + lc;
    #pragma unroll
    for (int kc=0;kc<4;kc++)
      af[rt][kc] = *(const short8*)(A + row*128 + kc*32 + q4*8);
  }

  f32x4 acc[2][8];
  #pragma unroll
  for (int rt=0;rt<2;rt++)
    #pragma unroll
    for (int ct=0;ct<8;ct++) acc[rt][ct] = (f32x4){0.f,0.f,0.f,0.f};

  __syncthreads();

  #pragma unroll
  for (int kc=0;kc<4;kc++){
    #pragma unroll
    for (int ct=0;ct<8;ct++){
      short8 bf = *(const short8*)&Bt[ct*16 + lc][kc*32 + q4*8];
      acc[0][ct] = __builtin_amdgcn_mfma_f32_16x16x32_bf16(af[0][kc], bf, acc[0][ct], 0,0,0);
      acc[1][ct] = __builtin_amdgcn_mfma_f32_16x16x32_bf16(af[1][kc], bf, acc[1][ct], 0,0,0);
    }
  }

  #pragma unroll
  for (int ct=0;ct<8;ct++){
    float ps = acc[0][ct][0]+acc[0][ct][1]+acc[0][ct][2]+acc[0][ct][3]
             + acc[1][ct][0]+acc[1][ct][1]+acc[1][ct][2]+acc[1][ct][3];
    ps += __shfl_xor(ps, 16);
    ps += __shfl_xor(ps, 32);
    if (q4 == 0) pools[w][ct*16 + lc] = ps;
  }
  __syncthreads();

  if (tid < 128){
    int c = tid;
    pooled[0][c] = (pools[0][c] + pools[1][c]) * (1.0f/64.0f) + bias[c];
    pooled[1][c] = (pools[2][c] + pools[3][c]) * (1.0f/64.0f) + bias[c];
  }
  __syncthreads();

  if (tid < 128){
    int g = tid >> 6, tp = tid & 63;
    float hh = b1[tp];
    for (int c=0;c<128;c++) hh = fmaf(pooled[g][c], W1[c*64 + tp], hh);
    hh = fmaxf(hh, 0.0f);
    float v = hh * W2[tp];
    #pragma unroll
    for (int off=32; off>0; off>>=1) v += __shfl_down(v, off);
    if (tp == 0) out[blockIdx.x*2 + g] = v + b2[0];
  }
}

extern "C" void kernel_launch(void* const* d_in, const int* in_sizes, int n_in,
                              void* d_out, int out_size, void* d_ws, size_t ws_size,
                              hipStream_t stream){
  const float* x     = (const float*)d_in[0];
  const int*   ei    = (const int*)d_in[1];
  const float* perres= (const float*)d_in[3];
  const float* W0 = (const float*)d_in[4];
  const float* b0 = (const float*)d_in[5];
  const float* W1 = (const float*)d_in[6];  const float* b1 = (const float*)d_in[7];
  const float* W2 = (const float*)d_in[8];  const float* b2 = (const float*)d_in[9];
  const float* bng = (const float*)d_in[10]; const float* bnb = (const float*)d_in[11];
  const float* bnm = (const float*)d_in[12]; const float* bnv = (const float*)d_in[13];
  const float* resW = (const float*)d_in[14]; const float* resb = (const float*)d_in[15];
  const float* inW  = (const float*)d_in[16]; const float* inb  = (const float*)d_in[17];
  const float* outW = (const float*)d_in[18]; const float* outb = (const float*)d_in[19];
  const float* cW1 = (const float*)d_in[20]; const float* cb1 = (const float*)d_in[21];
  const float* cW2 = (const float*)d_in[22]; const float* cb2 = (const float*)d_in[23];
  float* out = (float*)d_out;

  char* ws = (char*)d_ws;
  size_t off = 0;
  auto alloc = [&](size_t bytes) -> char* {
    char* p = ws + off;
    off += (bytes + 255) & ~(size_t)255;
    return p;
  };
  float* dinv    = (float*)alloc((size_t)N_NODES*4);
  int*   cnt     = (int*)  alloc((size_t)N_NODES*4);
  int*   cursor  = (int*)  alloc((size_t)N_NODES*4);
  int*   csr_off = (int*)  alloc((size_t)(N_NODES+1)*4);
  int2*  csr_ev  = (int2*) alloc((size_t)N_EDGES*8);
  int*   part    = (int*)  alloc((size_t)256*4);
  unsigned short* mb  = (unsigned short*)alloc((size_t)N_NODES*H*2);  // bf16: m / o
  unsigned short* hb  = (unsigned short*)alloc((size_t)N_NODES*H*2);  // bf16: h
  unsigned short* resbuf = (unsigned short*)alloc((size_t)R_RES*H*2); // bf16
  unsigned short* Kfr = (unsigned short*)alloc((size_t)R_RES*H*2);    // K fragment-major
  unsigned short* Vfr = (unsigned short*)alloc((size_t)H*R_RES*2);    // V fragment-major
  if (off > ws_size) return;

  const int* srcI = ei;
  const int* dstI = ei + N_EDGES;

  // CSR build (parallel 3-phase scan)
  (void)hipMemsetAsync(cnt, 0, (size_t)N_NODES*4, stream);
  k_count<<<N_EDGES/256, 256, 0, stream>>>(dstI, cnt, N_EDGES);
  k_part <<<N_NODES/256, 256, 0, stream>>>(cnt, part);
  k_scanp<<<1, 256, 0, stream>>>(part);
  k_apply<<<N_NODES/256, 256, 0, stream>>>(cnt, part, csr_off, cursor, dinv);
  k_fill <<<N_EDGES/256, 256, 0, stream>>>(srcI, dstI, dinv, cursor, csr_ev, N_EDGES);

  const int NB = N_NODES/128;
  const int AGB = N_NODES/16;   // 16 nodes per 256-thread block (R13 config)
  // GCN: layer 0 (K=7 VALU), layers 1/2 via MFMA
  k_lin0<<<N_NODES/4, 256, 0, stream>>>(x, W0, mb);
  k_agg<<<AGB, 256, 0, stream>>>(mb, csr_off, csr_ev, dinv, b0, bng,     bnb,     bnm,     bnv,     hb);
  k_gemm_mfma<<<NB, 256, 0, stream>>>(hb, W1, nullptr, mb, 0, 0);
  k_agg<<<AGB, 256, 0, stream>>>(mb, csr_off, csr_ev, dinv, b1, bng+128, bnb+128, bnm+128, bnv+128, hb);
  k_gemm_mfma<<<NB, 256, 0, stream>>>(hb, W2, nullptr, mb, 0, 0);
  k_agg<<<AGB, 256, 0, stream>>>(mb, csr_off, csr_ev, dinv, b2, bng+256, bnb+256, bnm+256, bnv+256, hb);

  // residue chain: res-proj (K=25), then fused K+V projection writing fragment-major directly
  k_gemm<<<R_RES/128, 256, 0, stream>>>(perres, resW, resb, resbuf, 25, 0, 1);
  k_kv<<<8, 256, 0, stream>>>(resbuf, inW, inb, Kfr, Vfr);

  // fused q-proj + attention (o -> mb)
  dim3 agrid(N_NODES/256, NH);
  k_attn<<<agrid, 256, 0, stream>>>(hb, inW, inb, Kfr, Vfr, mb);

  // fused out-proj + mean pool + classifier
  k_gemm_out<<<NB, 256, 0, stream>>>(mb, outW, outb, cW1, cb1, cW2, cb2, out);
}

// Round 16
// 364.043 us; speedup vs baseline: 1.1673x; 1.0322x over previous
//
#include <hip/hip_runtime.h>
#include <math.h>

#define N_NODES 65536
#define N_EDGES 524288
#define N_GRAPHS 1024
#define H 128
#define R_RES 512
#define NH 4
#define HD 32
#define D_IN 7
#define EPS 1e-5f

typedef __attribute__((ext_vector_type(8))) short short8;
typedef __attribute__((ext_vector_type(4))) short short4v;
typedef __attribute__((ext_vector_type(4))) float f32x4;
typedef __attribute__((ext_vector_type(4))) unsigned uint4v;
typedef __attribute__((ext_vector_type(2))) unsigned uint2v;
typedef __attribute__((ext_vector_type(4))) unsigned short us4;

#if __has_builtin(__builtin_amdgcn_exp2f)
#define EXP2F __builtin_amdgcn_exp2f
#else
#define EXP2F exp2f
#endif
#if __has_builtin(__builtin_amdgcn_rcpf)
#define RCPF __builtin_amdgcn_rcpf
#else
#define RCPF(x) (1.0f/(x))
#endif

// K=16 bf16 MFMA (v_mfma_f32_16x16x16_bf16; builtin only visible in device pass)
__device__ __forceinline__ f32x4 mfma_k16(short4v a, short4v b, f32x4 c){
#if defined(__HIP_DEVICE_COMPILE__)
  return __builtin_amdgcn_mfma_f32_16x16x16bf16_1k(a, b, c, 0, 0, 0);
#else
  (void)a; (void)b; return c;   // host pass stub, never executed
#endif
}

// round-half-up bf16 (1 add; max 0.5ulp)
__device__ __forceinline__ unsigned short rnd_bf16(float f){
  return (unsigned short)((__builtin_bit_cast(unsigned, f) + 0x8000u) >> 16);
}
// pack two floats -> bf16x2 in one v_perm
__device__ __forceinline__ unsigned pk_bf16(float lo, float hi){
  unsigned a = __builtin_bit_cast(unsigned, lo) + 0x8000u;
  unsigned b = __builtin_bit_cast(unsigned, hi) + 0x8000u;
  return __builtin_amdgcn_perm(b, a, 0x07060302u);
}
__device__ __forceinline__ float bflo(unsigned u){ return __builtin_bit_cast(float, u << 16); }
__device__ __forceinline__ float bfhi(unsigned u){ return __builtin_bit_cast(float, u & 0xFFFF0000u); }

// accumulate 8 bf16 lanes of u (4 dwords) scaled by wgt into a[8]
__device__ __forceinline__ void acc8(float* a, uint4v u, float wgt){
  a[0]=fmaf(bflo(u.x),wgt,a[0]); a[1]=fmaf(bfhi(u.x),wgt,a[1]);
  a[2]=fmaf(bflo(u.y),wgt,a[2]); a[3]=fmaf(bfhi(u.y),wgt,a[3]);
  a[4]=fmaf(bflo(u.z),wgt,a[4]); a[5]=fmaf(bfhi(u.z),wgt,a[5]);
  a[6]=fmaf(bflo(u.w),wgt,a[6]); a[7]=fmaf(bfhi(u.w),wgt,a[7]);
}

// ---------------- CSR build ----------------
__global__ __launch_bounds__(256) void k_count(const int* __restrict__ dst, int* __restrict__ cnt, int E){
  int e = blockIdx.x*256 + threadIdx.x;
  if (e < E) atomicAdd(&cnt[dst[e]], 1);
}

__global__ __launch_bounds__(256) void k_part(const int* __restrict__ cnt, int* __restrict__ part){
  int i = blockIdx.x*256 + threadIdx.x;
  int v = cnt[i];
  #pragma unroll
  for (int off=1; off<64; off<<=1) v += __shfl_xor(v, off);
  __shared__ int red[4];
  if ((threadIdx.x & 63) == 0) red[threadIdx.x >> 6] = v;
  __syncthreads();
  if (threadIdx.x == 0) part[blockIdx.x] = red[0]+red[1]+red[2]+red[3];
}

__global__ __launch_bounds__(256) void k_scanp(int* __restrict__ part){
  __shared__ int s[256];
  int t = threadIdx.x;
  int v = part[t];
  s[t] = v;
  __syncthreads();
  for (int off=1; off<256; off<<=1){
    int u = (t >= off) ? s[t-off] : 0;
    __syncthreads();
    s[t] += u;
    __syncthreads();
  }
  part[t] = s[t] - v;
}

__global__ __launch_bounds__(256) void k_apply(const int* __restrict__ cnt, const int* __restrict__ part,
      int* __restrict__ csr_off, int* __restrict__ cursor, float* __restrict__ dinv){
  __shared__ int s[256];
  int b = blockIdx.x, t = threadIdx.x;
  int i = b*256 + t;
  int c = cnt[i];
  s[t] = c;
  __syncthreads();
  for (int off=1; off<256; off<<=1){
    int u = (t >= off) ? s[t-off] : 0;
    __syncthreads();
    s[t] += u;
    __syncthreads();
  }
  int o0 = part[b] + s[t] - c;
  csr_off[i] = o0;
  cursor[i] = o0;
  dinv[i] = rsqrtf(1.0f + (float)c);
  if (i == N_NODES-1) csr_off[N_NODES] = N_EDGES;
}

// edge record = {src, weight-bits} packed in int2 -> one dwordx2 per edge in k_agg
__global__ __launch_bounds__(256) void k_fill(const int* __restrict__ src, const int* __restrict__ dst,
      const float* __restrict__ dinv, int* __restrict__ cursor, int2* __restrict__ csr_ev, int E){
  int e = blockIdx.x*256 + threadIdx.x;
  if (e >= E) return;
  int s = src[e], d = dst[e];
  int p = atomicAdd(&cursor[d], 1);
  int2 rec;
  rec.x = s;
  rec.y = __builtin_bit_cast(int, dinv[s]*dinv[d]);
  csr_ev[p] = rec;
}

// ---------------- layer-0 aggregation on raw x (7 fp32 cols): xa = agg(x) ----------------
// 8 lanes per node (one col each, col<7 active), 2-edge unroll. Exploits agg(x@W)=agg(x)@W.
__global__ __launch_bounds__(256) void k_agg0(const float* __restrict__ x, const int* __restrict__ csr_off,
      const int2* __restrict__ csr_ev, const float* __restrict__ dinv, float* __restrict__ xa){
  int gt = blockIdx.x*256 + threadIdx.x;
  int col = gt & 7;
  int n = gt >> 3;
  int cc = (col < D_IN) ? col : 0;          // keep loads in-bounds for lane 7
  float dn = dinv[n];
  float a = x[(long)n*D_IN + cc] * (dn*dn); // self term
  int e0 = csr_off[n], e1 = csr_off[n+1];
  int e = e0;
  for (; e + 2 <= e1; e += 2){
    int2 p0 = csr_ev[e], p1 = csr_ev[e+1];
    float v0 = x[(long)p0.x*D_IN + cc];
    float v1 = x[(long)p1.x*D_IN + cc];
    a = fmaf(v0, __builtin_bit_cast(float, p0.y), a);
    a = fmaf(v1, __builtin_bit_cast(float, p1.y), a);
  }
  if (e < e1){
    int2 p0 = csr_ev[e];
    a = fmaf(x[(long)p0.x*D_IN + cc], __builtin_bit_cast(float, p0.y), a);
  }
  if (col < D_IN) xa[(long)n*D_IN + col] = a;
}

// ---------------- layer-0 projection + bias + BN + ReLU: hb = relu(BN(xa @ W0 + b0)) ----------------
__global__ __launch_bounds__(256) void k_lin0(const float* __restrict__ xa, const float* __restrict__ W0,
      const float* __restrict__ b0, const float* __restrict__ gamma, const float* __restrict__ beta,
      const float* __restrict__ mean, const float* __restrict__ var, unsigned short* __restrict__ out){
  int gid = blockIdx.x*256 + threadIdx.x;
  int l = threadIdx.x & 63;
  int n = __builtin_amdgcn_readfirstlane(gid >> 6);
  float a0 = 0.0f, a1 = 0.0f;
  #pragma unroll
  for (int k=0;k<D_IN;k++){
    float xv = xa[(long)n*D_IN + k];       // wave-uniform -> scalar load
    float2 wv = *(const float2*)(W0 + k*H + 2*l);
    a0 = fmaf(xv, wv.x, a0); a1 = fmaf(xv, wv.y, a1);
  }
  int c = 2*l;
  float r0, r1;
  {
    float sc = gamma[c] * rsqrtf(var[c] + EPS);
    r0 = fmaxf(sc*(a0 + b0[c] - mean[c]) + beta[c], 0.0f);
  }
  {
    int c1 = c+1;
    float sc = gamma[c1] * rsqrtf(var[c1] + EPS);
    r1 = fmaxf(sc*(a1 + b0[c1] - mean[c1]) + beta[c1], 0.0f);
  }
  *(unsigned*)(out + (long)n*H + c) = pk_bf16(r0, r1);
}

// ---------------- bf16 MFMA GEMM: C[M,128] = A_bf16[M,128] @ B (+bias) ----------------
// outMode: 0 = bf16 row-major, 1 = fp32 row-major
__global__ __launch_bounds__(256) void k_gemm_mfma(const unsigned short* __restrict__ A,
      const float* __restrict__ Bsrc, const float* __restrict__ bias, void* __restrict__ Cout,
      int transB, int outMode){
  __shared__ unsigned short Bt[128][136];
  int tid = threadIdx.x;
  long rowBase = (long)blockIdx.x * 128;
  int w = tid >> 6, l = tid & 63;
  int lc = l & 15, q4 = l >> 4;

  if (transB){
    for (int i = tid; i < 4096; i += 256){
      int c = i >> 5, seg = i & 31;
      float4 v = *(const float4*)(Bsrc + (long)c*128 + seg*4);
      uint2 p; p.x = pk_bf16(v.x, v.y); p.y = pk_bf16(v.z, v.w);
      *(uint2*)&Bt[c][seg*4] = p;
    }
  } else {
    for (int i = tid; i < 4096; i += 256){
      int k = i >> 5, seg = i & 31;
      float4 v = *(const float4*)(Bsrc + (long)k*128 + seg*4);
      Bt[seg*4+0][k] = rnd_bf16(v.x); Bt[seg*4+1][k] = rnd_bf16(v.y);
      Bt[seg*4+2][k] = rnd_bf16(v.z); Bt[seg*4+3][k] = rnd_bf16(v.w);
    }
  }

  short8 af[2][4];
  #pragma unroll
  for (int rt=0;rt<2;rt++){
    long row = rowBase + w*32 + rt*16 + lc;
    #pragma unroll
    for (int kc=0;kc<4;kc++)
      af[rt][kc] = *(const short8*)(A + row*128 + kc*32 + q4*8);
  }

  f32x4 acc[2][8];
  #pragma unroll
  for (int rt=0;rt<2;rt++)
    #pragma unroll
    for (int ct=0;ct<8;ct++) acc[rt][ct] = (f32x4){0.f,0.f,0.f,0.f};

  __syncthreads();

  #pragma unroll
  for (int kc=0;kc<4;kc++){
    #pragma unroll
    for (int ct=0;ct<8;ct++){
      short8 bf = *(const short8*)&Bt[ct*16 + lc][kc*32 + q4*8];
      acc[0][ct] = __builtin_amdgcn_mfma_f32_16x16x32_bf16(af[0][kc], bf, acc[0][ct], 0,0,0);
      acc[1][ct] = __builtin_amdgcn_mfma_f32_16x16x32_bf16(af[1][kc], bf, acc[1][ct], 0,0,0);
    }
  }

  float bv[8];
  #pragma unroll
  for (int ct=0;ct<8;ct++) bv[ct] = bias ? bias[ct*16 + lc] : 0.0f;
  #pragma unroll
  for (int rt=0;rt<2;rt++){
    #pragma unroll
    for (int ct=0;ct<8;ct++){
      int col = ct*16 + lc;
      float vv[4];
      #pragma unroll
      for (int i=0;i<4;i++) vv[i] = acc[rt][ct][i] + bv[ct];
      long row0 = rowBase + w*32 + rt*16 + q4*4;
      if (outMode == 0){
        #pragma unroll
        for (int i=0;i<4;i++) ((unsigned short*)Cout)[(row0+i)*128 + col] = rnd_bf16(vv[i]);
      } else {
        #pragma unroll
        for (int i=0;i<4;i++) ((float*)Cout)[(row0+i)*128 + col] = vv[i];
      }
    }
  }
}

// ---------------- fused K+V projection GEMM, writing fragment-major directly ----------------
// Grid = 8 blocks: b<4 -> K rows b*128.., b>=4 -> V rows (b-4)*128..
// Frag layout: F[h*16384 + rc*512 + lane*8 + j] (head stride 16384, chunk stride 512 shorts).
__global__ __launch_bounds__(256) void k_kv(const unsigned short* __restrict__ A,
      const float* __restrict__ inW, const float* __restrict__ inb,
      unsigned short* __restrict__ FK, unsigned short* __restrict__ FV){
  __shared__ unsigned short Bt[128][136];
  int tid = threadIdx.x;
  int blk = blockIdx.x;
  int isK = (blk < 4);
  const float* Bsrc = inW + (isK ? 128*128 : 256*128);
  const float* bias = inb + (isK ? 128 : 256);
  long rowBase = (long)(blk & 3) * 128;
  int w = tid >> 6, l = tid & 63;
  int lc = l & 15, q4 = l >> 4;

  for (int i = tid; i < 4096; i += 256){    // B = W^T: B(k,c) = Bsrc[c*128+k]
    int c = i >> 5, seg = i & 31;
    float4 v = *(const float4*)(Bsrc + (long)c*128 + seg*4);
    uint2 p; p.x = pk_bf16(v.x, v.y); p.y = pk_bf16(v.z, v.w);
    *(uint2*)&Bt[c][seg*4] = p;
  }

  short8 af[2][4];
  #pragma unroll
  for (int rt=0;rt<2;rt++){
    long row = rowBase + w*32 + rt*16 + lc;
    #pragma unroll
    for (int kc=0;kc<4;kc++)
      af[rt][kc] = *(const short8*)(A + row*128 + kc*32 + q4*8);
  }

  f32x4 acc[2][8];
  #pragma unroll
  for (int rt=0;rt<2;rt++)
    #pragma unroll
    for (int ct=0;ct<8;ct++) acc[rt][ct] = (f32x4){0.f,0.f,0.f,0.f};

  __syncthreads();

  #pragma unroll
  for (int kc=0;kc<4;kc++){
    #pragma unroll
    for (int ct=0;ct<8;ct++){
      short8 bf = *(const short8*)&Bt[ct*16 + lc][kc*32 + q4*8];
      acc[0][ct] = __builtin_amdgcn_mfma_f32_16x16x32_bf16(af[0][kc], bf, acc[0][ct], 0,0,0);
      acc[1][ct] = __builtin_amdgcn_mfma_f32_16x16x32_bf16(af[1][kc], bf, acc[1][ct], 0,0,0);
    }
  }

  float bv[8];
  #pragma unroll
  for (int ct=0;ct<8;ct++) bv[ct] = bias[ct*16 + lc];
  #pragma unroll
  for (int rt=0;rt<2;rt++){
    long rc = ((blk & 3)*128 + w*32 + rt*16) >> 4;    // res-chunk index (0..31)
    #pragma unroll
    for (int ct=0;ct<8;ct++){
      float vv[4];
      #pragma unroll
      for (int i=0;i<4;i++) vv[i] = acc[rt][ct][i] + bv[ct];
      int h = ct >> 1;
      if (isK){
        int q4d = (ct*2 + (lc >> 3)) & 3;
        long base = (long)h*16384 + rc*512 + q4d*128 + (q4*4)*8 + (lc & 7);
        #pragma unroll
        for (int i=0;i<4;i++) FK[base + i*8] = rnd_bf16(vv[i]);
      } else {
        long base = (long)h*16384 + rc*512 + q4*128 + lc*8 + (ct & 1)*4;
        us4 p = { rnd_bf16(vv[0]), rnd_bf16(vv[1]), rnd_bf16(vv[2]), rnd_bf16(vv[3]) };
        *(us4*)(FV + base) = p;
      }
    }
  }
}

// ---------------- GCN aggregation + bias + BN + ReLU, bf16 in/out (layers 1/2) ----------------
// 16 lanes per node (8 cols/lane, dwordx4 gathers), 4 nodes/wave, 4-edge unroll. (R13 config)
__global__ __launch_bounds__(256) void k_agg(const unsigned short* __restrict__ m, const int* __restrict__ csr_off,
      const int2* __restrict__ csr_ev, const float* __restrict__ dinv,
      const float* __restrict__ b, const float* __restrict__ gamma, const float* __restrict__ beta,
      const float* __restrict__ mean, const float* __restrict__ var, unsigned short* __restrict__ out){
  int gt = blockIdx.x*256 + threadIdx.x;
  int li = gt & 15;
  int n = gt >> 4;
  int c = li*8;
  float dn = dinv[n], sn = dn*dn;
  float a[8];
  {
    uint4v u = *(const uint4v*)(m + (long)n*H + c);
    a[0]=bflo(u.x)*sn; a[1]=bfhi(u.x)*sn; a[2]=bflo(u.y)*sn; a[3]=bfhi(u.y)*sn;
    a[4]=bflo(u.z)*sn; a[5]=bfhi(u.z)*sn; a[6]=bflo(u.w)*sn; a[7]=bfhi(u.w)*sn;
  }
  int e0 = csr_off[n], e1 = csr_off[n+1];
  int e = e0;
  for (; e + 4 <= e1; e += 4){
    int2 p0 = csr_ev[e],   p1 = csr_ev[e+1];
    int2 p2 = csr_ev[e+2], p3 = csr_ev[e+3];
    uint4v u0 = *(const uint4v*)(m + (long)p0.x*H + c);
    uint4v u1 = *(const uint4v*)(m + (long)p1.x*H + c);
    uint4v u2 = *(const uint4v*)(m + (long)p2.x*H + c);
    uint4v u3 = *(const uint4v*)(m + (long)p3.x*H + c);
    acc8(a, u0, __builtin_bit_cast(float, p0.y));
    acc8(a, u1, __builtin_bit_cast(float, p1.y));
    acc8(a, u2, __builtin_bit_cast(float, p2.y));
    acc8(a, u3, __builtin_bit_cast(float, p3.y));
  }
  for (; e < e1; e++){
    int2 p0 = csr_ev[e];
    uint4v u0 = *(const uint4v*)(m + (long)p0.x*H + c);
    acc8(a, u0, __builtin_bit_cast(float, p0.y));
  }
  float4 g0 = *(const float4*)(gamma + c), g1 = *(const float4*)(gamma + c + 4);
  float4 v0 = *(const float4*)(var   + c), v1 = *(const float4*)(var   + c + 4);
  float4 b0 = *(const float4*)(b     + c), b1 = *(const float4*)(b     + c + 4);
  float4 m0 = *(const float4*)(mean  + c), m1 = *(const float4*)(mean  + c + 4);
  float4 t0 = *(const float4*)(beta  + c), t1 = *(const float4*)(beta  + c + 4);
  float r[8];
  r[0]=fmaxf(g0.x*rsqrtf(v0.x+EPS)*(a[0]+b0.x-m0.x)+t0.x, 0.f);
  r[1]=fmaxf(g0.y*rsqrtf(v0.y+EPS)*(a[1]+b0.y-m0.y)+t0.y, 0.f);
  r[2]=fmaxf(g0.z*rsqrtf(v0.z+EPS)*(a[2]+b0.z-m0.z)+t0.z, 0.f);
  r[3]=fmaxf(g0.w*rsqrtf(v0.w+EPS)*(a[3]+b0.w-m0.w)+t0.w, 0.f);
  r[4]=fmaxf(g1.x*rsqrtf(v1.x+EPS)*(a[4]+b1.x-m1.x)+t1.x, 0.f);
  r[5]=fmaxf(g1.y*rsqrtf(v1.y+EPS)*(a[5]+b1.y-m1.y)+t1.y, 0.f);
  r[6]=fmaxf(g1.z*rsqrtf(v1.z+EPS)*(a[6]+b1.z-m1.z)+t1.z, 0.f);
  r[7]=fmaxf(g1.w*rsqrtf(v1.w+EPS)*(a[7]+b1.w-m1.w)+t1.w, 0.f);
  uint4v p;
  p.x = pk_bf16(r[0],r[1]); p.y = pk_bf16(r[2],r[3]);
  p.z = pk_bf16(r[4],r[5]); p.w = pk_bf16(r[6],r[7]);
  *(uint4v*)(out + (long)n*H + c) = p;
}

// ---------------- fp32 GEMM (res projection, K=25), bf16 out ----------------
__global__ __launch_bounds__(256,2) void k_gemm(const float* __restrict__ A, const float* __restrict__ B,
      const float* __restrict__ bias, void* __restrict__ C, int K, int transB, int outBf16){
  __shared__ float Bs[128][132];
  __shared__ float As[16][128];
  int tid = threadIdx.x;
  long rowBase = (long)blockIdx.x * 128;

  if (!transB){
    for (int idx = tid; idx < 128*128; idx += 256){
      int k = idx >> 7, c = idx & 127;
      Bs[k][c] = (k < K) ? B[(long)k*128 + c] : 0.0f;
    }
  } else {
    for (int idx = tid; idx < 128*128; idx += 256){
      int c = idx >> 7, k = idx & 127;
      Bs[k][c] = (k < K) ? B[(long)c*K + k] : 0.0f;
    }
  }

  float acc[8][8];
  #pragma unroll
  for (int i=0;i<8;i++)
    #pragma unroll
    for (int j=0;j<8;j++) acc[i][j] = 0.0f;

  int rg = tid >> 4, cg = tid & 15;
  int r0 = rg*8, c0 = cg*8;
  int srow = tid >> 1, skoff = (tid & 1)*8;
  const bool fast = ((K & 15) == 0);

  for (int k0 = 0; k0 < K; k0 += 16){
    __syncthreads();
    const float* ap = A + (rowBase + srow)*K + k0 + skoff;
    if (fast){
      float4 v0 = *(const float4*)(ap);
      float4 v1 = *(const float4*)(ap + 4);
      As[skoff+0][srow] = v0.x; As[skoff+1][srow] = v0.y;
      As[skoff+2][srow] = v0.z; As[skoff+3][srow] = v0.w;
      As[skoff+4][srow] = v1.x; As[skoff+5][srow] = v1.y;
      As[skoff+6][srow] = v1.z; As[skoff+7][srow] = v1.w;
    } else {
      #pragma unroll
      for (int j=0;j<8;j++){
        int kk = k0 + skoff + j;
        As[skoff+j][srow] = (kk < K) ? ap[j] : 0.0f;
      }
    }
    __syncthreads();
    #pragma unroll
    for (int k=0;k<16;k++){
      float4 a0 = *(const float4*)(&As[k][r0]);
      float4 a1 = *(const float4*)(&As[k][r0+4]);
      float4 b0 = *(const float4*)(&Bs[k0+k][c0]);
      float4 b1 = *(const float4*)(&Bs[k0+k][c0+4]);
      float a[8] = {a0.x,a0.y,a0.z,a0.w,a1.x,a1.y,a1.z,a1.w};
      float b[8] = {b0.x,b0.y,b0.z,b0.w,b1.x,b1.y,b1.z,b1.w};
      #pragma unroll
      for (int i=0;i<8;i++)
        #pragma unroll
        for (int j=0;j<8;j++)
          acc[i][j] = fmaf(a[i], b[j], acc[i][j]);
    }
  }

  #pragma unroll
  for (int i=0;i<8;i++){
    float o[8];
    #pragma unroll
    for (int j=0;j<8;j++) o[j] = acc[i][j] + (bias ? bias[c0+j] : 0.0f);
    long row = rowBase + r0 + i;
    if (outBf16){
      uint4v p;
      p.x = pk_bf16(o[0],o[1]); p.y = pk_bf16(o[2],o[3]);
      p.z = pk_bf16(o[4],o[5]); p.w = pk_bf16(o[6],o[7]);
      *(uint4v*)((unsigned short*)C + row*128 + c0) = p;
    } else {
      float* cp = (float*)C + row*128 + c0;
      *(float4*)cp = (float4){o[0],o[1],o[2],o[3]};
      *(float4*)(cp+4) = (float4){o[4],o[5],o[6],o[7]};
    }
  }
}

// ---------------- fused q-proj + flash cross-attention, shape-mixed MFMA (R13 config) ----------------
__global__ __launch_bounds__(256,4) void k_attn(const unsigned short* __restrict__ hb,
      const float* __restrict__ inW, const float* __restrict__ inb,
      const unsigned short* __restrict__ Kf, const unsigned short* __restrict__ Vf,
      unsigned short* __restrict__ obuf){
  int tid = threadIdx.x;
  int h = blockIdx.y;
  int w = tid >> 6, l = tid & 63;
  int lc = l & 15, q4 = l >> 4;
  long nb = (long)blockIdx.x*256 + w*64;
  const float scale = 0.25503489f;   // log2(e)/sqrt(32)

  int srcA = lc + (q4 & 1)*32;
  int srcB = srcA + 16;
  bool hi = (q4 >> 1) != 0;

  // Wq A-frags (m=dim_local, k=hid)
  short8 wq[2][4];
  #pragma unroll
  for (int t=0;t<2;t++){
    #pragma unroll
    for (int kc=0;kc<4;kc++){
      const float* wp = inW + (long)(h*32 + t*16 + lc)*128 + kc*32 + q4*8;
      float4 x0 = *(const float4*)wp;
      float4 x1 = *(const float4*)(wp+4);
      uint4v p; p.x = pk_bf16(x0.x,x0.y); p.y = pk_bf16(x0.z,x0.w);
      p.z = pk_bf16(x1.x,x1.y); p.w = pk_bf16(x1.z,x1.w);
      wq[t][kc] = __builtin_bit_cast(short8, p);
    }
  }
  float bq0[4], bq1[4];
  #pragma unroll
  for (int i=0;i<4;i++){ bq0[i] = inb[h*32 + q4*4 + i]; bq1[i] = inb[h*32 + 16 + q4*4 + i]; }

  // q^T = Wq @ h^T per 16-node tile, C-layout -> K=32 B-frag turn (prologue only)
  short8 qB[4];
  #pragma unroll
  for (int nt=0;nt<4;nt++){
    short8 hf[4];
    #pragma unroll
    for (int kc=0;kc<4;kc++)
      hf[kc] = *(const short8*)(hb + (nb + nt*16 + lc)*128 + kc*32 + q4*8);
    f32x4 qa0 = (f32x4){0.f,0.f,0.f,0.f};
    f32x4 qa1 = (f32x4){0.f,0.f,0.f,0.f};
    #pragma unroll
    for (int kc=0;kc<4;kc++){
      qa0 = __builtin_amdgcn_mfma_f32_16x16x32_bf16(wq[0][kc], hf[kc], qa0, 0,0,0);
      qa1 = __builtin_amdgcn_mfma_f32_16x16x32_bf16(wq[1][kc], hf[kc], qa1, 0,0,0);
    }
    unsigned P0 = pk_bf16((qa0[0]+bq0[0])*scale, (qa0[1]+bq0[1])*scale);
    unsigned P1 = pk_bf16((qa0[2]+bq0[2])*scale, (qa0[3]+bq0[3])*scale);
    unsigned P2 = pk_bf16((qa1[0]+bq1[0])*scale, (qa1[1]+bq1[1])*scale);
    unsigned P3 = pk_bf16((qa1[2]+bq1[2])*scale, (qa1[3]+bq1[3])*scale);
    unsigned x0 = __shfl(P0, srcA), x1 = __shfl(P1, srcA), x2 = __shfl(P2, srcA), x3 = __shfl(P3, srcA);
    unsigned y0 = __shfl(P0, srcB), y1 = __shfl(P1, srcB), y2 = __shfl(P2, srcB), y3 = __shfl(P3, srcB);
    uint4v bp; bp.x = hi?x2:x0; bp.y = hi?x3:x1; bp.z = hi?y2:y0; bp.w = hi?y3:y1;
    qB[nt] = __builtin_bit_cast(short8, bp);
  }

  const short4v ones4 = {(short)0x3F80,(short)0x3F80,(short)0x3F80,(short)0x3F80};
  f32x4 oA[4], oB[4], os[4];
  #pragma unroll
  for (int nt=0;nt<4;nt++){
    oA[nt] = (f32x4){0.f,0.f,0.f,0.f};
    oB[nt] = (f32x4){0.f,0.f,0.f,0.f};
    os[nt] = (f32x4){0.f,0.f,0.f,0.f};
  }

  // fragment-major: head stride 16384 shorts, chunk stride 512 shorts (1KB)
  const unsigned short* Kp = Kf + (long)h*16384 + (long)l*8;
  const unsigned short* Vp = Vf + (long)h*16384 + (long)l*8;

  for (int rc = 0; rc < 32; rc++){
    short8 kf = *(const short8*)(Kp + rc*512);            // coalesced 1KB
    uint4v vv = *(const uint4v*)(Vp + rc*512);            // coalesced 1KB: [vfA|vfB]
    uint2v va = {vv.x, vv.y}, vb = {vv.z, vv.w};
    short4v vfA = __builtin_bit_cast(short4v, va);
    short4v vfB = __builtin_bit_cast(short4v, vb);
    #pragma unroll
    for (int nt=0;nt<4;nt++){
      f32x4 z = {0.f,0.f,0.f,0.f};
      f32x4 s = __builtin_amdgcn_mfma_f32_16x16x32_bf16(kf, qB[nt], z, 0,0,0);
      float e0 = EXP2F(s[0]), e1 = EXP2F(s[1]), e2 = EXP2F(s[2]), e3 = EXP2F(s[3]);
      uint2v pk2; pk2.x = pk_bf16(e0, e1); pk2.y = pk_bf16(e2, e3);
      short4v pf = __builtin_bit_cast(short4v, pk2);      // P^T B-frag, directly
      oA[nt] = mfma_k16(vfA,   pf, oA[nt]);
      oB[nt] = mfma_k16(vfB,   pf, oB[nt]);
      os[nt] = mfma_k16(ones4, pf, os[nt]);               // softmax denominators
    }
  }

  #pragma unroll
  for (int nt=0;nt<4;nt++){
    float inv = RCPF(os[nt][0]);
    long node = nb + nt*16 + lc;
    us4 a = { rnd_bf16(oA[nt][0]*inv), rnd_bf16(oA[nt][1]*inv),
              rnd_bf16(oA[nt][2]*inv), rnd_bf16(oA[nt][3]*inv) };
    us4 b = { rnd_bf16(oB[nt][0]*inv), rnd_bf16(oB[nt][1]*inv),
              rnd_bf16(oB[nt][2]*inv), rnd_bf16(oB[nt][3]*inv) };
    *(us4*)(obuf + node*128 + h*32 + q4*4) = a;
    *(us4*)(obuf + node*128 + h*32 + 16 + q4*4) = b;
  }
}

// ---------------- fused out-proj + mean-pool + classifier: block = 128 nodes = 2 graphs ----------------
__global__ __launch_bounds__(256) void k_gemm_out(const unsigned short* __restrict__ A,
      const float* __restrict__ Bsrc, const float* __restrict__ bias,
      const float* __restrict__ W1, const float* __restrict__ b1,
      const float* __restrict__ W2, const float* __restrict__ b2, float* __restrict__ out){
  __shared__ unsigned short Bt[128][136];
  __shared__ float pools[4][128];
  __shared__ float pooled[2][128];
  int tid = threadIdx.x;
  long rowBase = (long)blockIdx.x * 128;
  int w = tid >> 6, l = tid & 63;
  int lc = l & 15, q4 = l >> 4;

  for (int i = tid; i < 4096; i += 256){
    int c = i >> 5, seg = i & 31;
    float4 v = *(const float4*)(Bsrc + (long)c*128 + seg*4);
    uint2 p; p.x = pk_bf16(v.x, v.y); p.y = pk_bf16(v.z, v.w);
    *(uint2*)&Bt[c][seg*4] = p;
  }

  short8 af[2][4];
  #pragma unroll
  for (int rt=0;rt<2;rt++){
    long row = rowBase + w*32 + rt*16 + lc;
    #pragma unroll
    for (int kc=0;kc<4;kc++)
      af[rt][kc] = *(const short8*)(A + row*128 + kc*32 + q4*8);
  }

  f32x4 acc[2][8];
  #pragma unroll
  for (int rt=0;rt<2;rt++)
    #pragma unroll
    for (int ct=0;ct<8;ct++) acc[rt][ct] = (f32x4){0.f,0.f,0.f,0.f};

  __syncthreads();

  #pragma unroll
  for (int kc=0;kc<4;kc++){
    #pragma unroll
    for (int ct=0;ct<8;ct++){
      short8 bf = *(const short8*)&Bt[ct*16 + lc][kc*32 + q4*8];
      acc[0][ct] = __builtin_amdgcn_mfma_f32_16x16x32_bf16(af[0][kc], bf, acc[0][ct], 0,0,0);
      acc[1][ct] = __builtin_amdgcn_mfma_f32_16x16x32_bf16(af[1][kc], bf, acc[1][ct], 0,0,0);
    }
  }

  #pragma unroll
  for (int ct=0;ct<8;ct++){
    float ps = acc[0][ct][0]+acc[0][ct][1]+acc[0][ct][2]+acc[0][ct][3]
             + acc[1][ct][0]+acc[1][ct][1]+acc[1][ct][2]+acc[1][ct][3];
    ps += __shfl_xor(ps, 16);
    ps += __shfl_xor(ps, 32);
    if (q4 == 0) pools[w][ct*16 + lc] = ps;
  }
  __syncthreads();

  if (tid < 128){
    int c = tid;
    pooled[0][c] = (pools[0][c] + pools[1][c]) * (1.0f/64.0f) + bias[c];
    pooled[1][c] = (pools[2][c] + pools[3][c]) * (1.0f/64.0f) + bias[c];
  }
  __syncthreads();

  if (tid < 128){
    int g = tid >> 6, tp = tid & 63;
    float hh = b1[tp];
    for (int c=0;c<128;c++) hh = fmaf(pooled[g][c], W1[c*64 + tp], hh);
    hh = fmaxf(hh, 0.0f);
    float v = hh * W2[tp];
    #pragma unroll
    for (int off=32; off>0; off>>=1) v += __shfl_down(v, off);
    if (tp == 0) out[blockIdx.x*2 + g] = v + b2[0];
  }
}

extern "C" void kernel_launch(void* const* d_in, const int* in_sizes, int n_in,
                              void* d_out, int out_size, void* d_ws, size_t ws_size,
                              hipStream_t stream){
  const float* x     = (const float*)d_in[0];
  const int*   ei    = (const int*)d_in[1];
  const float* perres= (const float*)d_in[3];
  const float* W0 = (const float*)d_in[4];
  const float* b0 = (const float*)d_in[5];
  const float* W1 = (const float*)d_in[6];  const float* b1 = (const float*)d_in[7];
  const float* W2 = (const float*)d_in[8];  const float* b2 = (const float*)d_in[9];
  const float* bng = (const float*)d_in[10]; const float* bnb = (const float*)d_in[11];
  const float* bnm = (const float*)d_in[12]; const float* bnv = (const float*)d_in[13];
  const float* resW = (const float*)d_in[14]; const float* resb = (const float*)d_in[15];
  const float* inW  = (const float*)d_in[16]; const float* inb  = (const float*)d_in[17];
  const float* outW = (const float*)d_in[18]; const float* outb = (const float*)d_in[19];
  const float* cW1 = (const float*)d_in[20]; const float* cb1 = (const float*)d_in[21];
  const float* cW2 = (const float*)d_in[22]; const float* cb2 = (const float*)d_in[23];
  float* out = (float*)d_out;

  char* ws = (char*)d_ws;
  size_t off = 0;
  auto alloc = [&](size_t bytes) -> char* {
    char* p = ws + off;
    off += (bytes + 255) & ~(size_t)255;
    return p;
  };
  float* dinv    = (float*)alloc((size_t)N_NODES*4);
  int*   cnt     = (int*)  alloc((size_t)N_NODES*4);
  int*   cursor  = (int*)  alloc((size_t)N_NODES*4);
  int*   csr_off = (int*)  alloc((size_t)(N_NODES+1)*4);
  int2*  csr_ev  = (int2*) alloc((size_t)N_EDGES*8);
  int*   part    = (int*)  alloc((size_t)256*4);
  float* xa      = (float*)alloc((size_t)N_NODES*D_IN*4);             // fp32 agg(x)
  unsigned short* mb  = (unsigned short*)alloc((size_t)N_NODES*H*2);  // bf16: m / o
  unsigned short* hb  = (unsigned short*)alloc((size_t)N_NODES*H*2);  // bf16: h
  unsigned short* resbuf = (unsigned short*)alloc((size_t)R_RES*H*2); // bf16
  unsigned short* Kfr = (unsigned short*)alloc((size_t)R_RES*H*2);    // K fragment-major
  unsigned short* Vfr = (unsigned short*)alloc((size_t)H*R_RES*2);    // V fragment-major
  if (off > ws_size) return;

  const int* srcI = ei;
  const int* dstI = ei + N_EDGES;

  // CSR build (parallel 3-phase scan)
  (void)hipMemsetAsync(cnt, 0, (size_t)N_NODES*4, stream);
  k_count<<<N_EDGES/256, 256, 0, stream>>>(dstI, cnt, N_EDGES);
  k_part <<<N_NODES/256, 256, 0, stream>>>(cnt, part);
  k_scanp<<<1, 256, 0, stream>>>(part);
  k_apply<<<N_NODES/256, 256, 0, stream>>>(cnt, part, csr_off, cursor, dinv);
  k_fill <<<N_EDGES/256, 256, 0, stream>>>(srcI, dstI, dinv, cursor, csr_ev, N_EDGES);

  const int NB = N_NODES/128;
  const int AGB = N_NODES/16;   // 16 nodes per 256-thread block (R13 config)
  // GCN layer 0: aggregate raw x (7 cols, agg(x)@W = agg(x@W)), then project+BN+ReLU
  k_agg0<<<N_NODES/32, 256, 0, stream>>>(x, csr_off, csr_ev, dinv, xa);
  k_lin0<<<N_NODES/4, 256, 0, stream>>>(xa, W0, b0, bng, bnb, bnm, bnv, hb);
  // layers 1/2 via MFMA GEMM + gather-agg
  k_gemm_mfma<<<NB, 256, 0, stream>>>(hb, W1, nullptr, mb, 0, 0);
  k_agg<<<AGB, 256, 0, stream>>>(mb, csr_off, csr_ev, dinv, b1, bng+128, bnb+128, bnm+128, bnv+128, hb);
  k_gemm_mfma<<<NB, 256, 0, stream>>>(hb, W2, nullptr, mb, 0, 0);
  k_agg<<<AGB, 256, 0, stream>>>(mb, csr_off, csr_ev, dinv, b2, bng+256, bnb+256, bnm+256, bnv+256, hb);

  // residue chain: res-proj (K=25), then fused K+V projection writing fragment-major directly
  k_gemm<<<R_RES/128, 256, 0, stream>>>(perres, resW, resb, resbuf, 25, 0, 1);
  k_kv<<<8, 256, 0, stream>>>(resbuf, inW, inb, Kfr, Vfr);

  // fused q-proj + attention (o -> mb)
  dim3 agrid(N_NODES/256, NH);
  k_attn<<<agrid, 256, 0, stream>>>(hb, inW, inb, Kfr, Vfr, mb);

  // fused out-proj + mean pool + classifier
  k_gemm_out<<<NB, 256, 0, stream>>>(mb, outW, outb, cW1, cb1, cW2, cb2, out);
}

// Round 17
// 338.921 us; speedup vs baseline: 1.2538x; 1.0741x over previous
//
#include <hip/hip_runtime.h>
#include <math.h>

#define N_NODES 65536
#define N_EDGES 524288
#define N_GRAPHS 1024
#define H 128
#define R_RES 512
#define NH 4
#define HD 32
#define D_IN 7
#define EPS 1e-5f

typedef __attribute__((ext_vector_type(8))) short short8;
typedef __attribute__((ext_vector_type(4))) short short4v;
typedef __attribute__((ext_vector_type(4))) float f32x4;
typedef __attribute__((ext_vector_type(4))) unsigned uint4v;
typedef __attribute__((ext_vector_type(2))) unsigned uint2v;
typedef __attribute__((ext_vector_type(4))) unsigned short us4;

#if __has_builtin(__builtin_amdgcn_exp2f)
#define EXP2F __builtin_amdgcn_exp2f
#else
#define EXP2F exp2f
#endif
#if __has_builtin(__builtin_amdgcn_rcpf)
#define RCPF __builtin_amdgcn_rcpf
#else
#define RCPF(x) (1.0f/(x))
#endif

// K=16 bf16 MFMA (builtin only visible in device pass)
__device__ __forceinline__ f32x4 mfma_k16(short4v a, short4v b, f32x4 c){
#if defined(__HIP_DEVICE_COMPILE__)
  return __builtin_amdgcn_mfma_f32_16x16x16bf16_1k(a, b, c, 0, 0, 0);
#else
  (void)a; (void)b; return c;
#endif
}

__device__ __forceinline__ unsigned short rnd_bf16(float f){
  return (unsigned short)((__builtin_bit_cast(unsigned, f) + 0x8000u) >> 16);
}
__device__ __forceinline__ unsigned pk_bf16(float lo, float hi){
  unsigned a = __builtin_bit_cast(unsigned, lo) + 0x8000u;
  unsigned b = __builtin_bit_cast(unsigned, hi) + 0x8000u;
  return __builtin_amdgcn_perm(b, a, 0x07060302u);
}
__device__ __forceinline__ float bflo(unsigned u){ return __builtin_bit_cast(float, u << 16); }
__device__ __forceinline__ float bfhi(unsigned u){ return __builtin_bit_cast(float, u & 0xFFFF0000u); }

__device__ __forceinline__ void acc8(float* a, uint4v u, float wgt){
  a[0]=fmaf(bflo(u.x),wgt,a[0]); a[1]=fmaf(bfhi(u.x),wgt,a[1]);
  a[2]=fmaf(bflo(u.y),wgt,a[2]); a[3]=fmaf(bfhi(u.y),wgt,a[3]);
  a[4]=fmaf(bflo(u.z),wgt,a[4]); a[5]=fmaf(bfhi(u.z),wgt,a[5]);
  a[6]=fmaf(bflo(u.w),wgt,a[6]); a[7]=fmaf(bfhi(u.w),wgt,a[7]);
}

// ---------------- CSR build ----------------
// count + per-edge rank within dst bucket (atomic return value)
__global__ __launch_bounds__(256) void k_count(const int* __restrict__ dst, int* __restrict__ cnt,
                                               int* __restrict__ rank, int E){
  int e = blockIdx.x*256 + threadIdx.x;
  if (e < E) rank[e] = atomicAdd(&cnt[dst[e]], 1);
}

__global__ __launch_bounds__(256) void k_part(const int* __restrict__ cnt, int* __restrict__ part){
  int i = blockIdx.x*256 + threadIdx.x;
  int v = cnt[i];
  #pragma unroll
  for (int off=1; off<64; off<<=1) v += __shfl_xor(v, off);
  __shared__ int red[4];
  if ((threadIdx.x & 63) == 0) red[threadIdx.x >> 6] = v;
  __syncthreads();
  if (threadIdx.x == 0) part[blockIdx.x] = red[0]+red[1]+red[2]+red[3];
}

__global__ __launch_bounds__(256) void k_scanp(int* __restrict__ part){
  __shared__ int s[256];
  int t = threadIdx.x;
  int v = part[t];
  s[t] = v;
  __syncthreads();
  for (int off=1; off<256; off<<=1){
    int u = (t >= off) ? s[t-off] : 0;
    __syncthreads();
    s[t] += u;
    __syncthreads();
  }
  part[t] = s[t] - v;
}

__global__ __launch_bounds__(256) void k_apply(const int* __restrict__ cnt, const int* __restrict__ part,
      int* __restrict__ csr_off, float* __restrict__ dinv){
  __shared__ int s[256];
  int b = blockIdx.x, t = threadIdx.x;
  int i = b*256 + t;
  int c = cnt[i];
  s[t] = c;
  __syncthreads();
  for (int off=1; off<256; off<<=1){
    int u = (t >= off) ? s[t-off] : 0;
    __syncthreads();
    s[t] += u;
    __syncthreads();
  }
  int o0 = part[b] + s[t] - c;
  csr_off[i] = o0;
  dinv[i] = rsqrtf(1.0f + (float)c);
  if (i == N_NODES-1) csr_off[N_NODES] = N_EDGES;
}

// atomic-free fill using rank
__global__ __launch_bounds__(256) void k_fill(const int* __restrict__ src, const int* __restrict__ dst,
      const int* __restrict__ rank, const int* __restrict__ csr_off, const float* __restrict__ dinv,
      int2* __restrict__ csr_ev, int E){
  int e = blockIdx.x*256 + threadIdx.x;
  if (e >= E) return;
  int s = src[e], d = dst[e];
  int p = csr_off[d] + rank[e];
  int2 rec;
  rec.x = s;
  rec.y = __builtin_bit_cast(int, dinv[s]*dinv[d]);
  csr_ev[p] = rec;
}

// ---------------- fused layer-0: agg(x) (7 cols) + projection + BN + ReLU ----------------
// Block = 32 nodes. Phase 1: 8 lanes/node aggregate into LDS. Phase 2: wave/node projection.
__global__ __launch_bounds__(256) void k_l0(const float* __restrict__ x, const int* __restrict__ csr_off,
      const int2* __restrict__ csr_ev, const float* __restrict__ dinv,
      const float* __restrict__ W0, const float* __restrict__ b0,
      const float* __restrict__ gamma, const float* __restrict__ beta,
      const float* __restrict__ mean, const float* __restrict__ var,
      unsigned short* __restrict__ out){
  __shared__ float xs[32][8];
  int t = threadIdx.x;
  long nb = (long)blockIdx.x*32;
  {
    int nl = t >> 3, col = t & 7;
    int n = (int)nb + nl;
    int cc = (col < D_IN) ? col : 0;
    float dn = dinv[n];
    float a = x[(long)n*D_IN + cc]*(dn*dn);
    int e0 = csr_off[n], e1 = csr_off[n+1];
    int e = e0;
    for (; e + 2 <= e1; e += 2){
      int2 p0 = csr_ev[e], p1 = csr_ev[e+1];
      a = fmaf(x[(long)p0.x*D_IN + cc], __builtin_bit_cast(float, p0.y), a);
      a = fmaf(x[(long)p1.x*D_IN + cc], __builtin_bit_cast(float, p1.y), a);
    }
    if (e < e1){
      int2 p0 = csr_ev[e];
      a = fmaf(x[(long)p0.x*D_IN + cc], __builtin_bit_cast(float, p0.y), a);
    }
    xs[nl][col] = a;     // col 7 holds junk, never read
  }
  __syncthreads();
  int w = t >> 6, l = t & 63;
  int c = 2*l;
  float sc0 = gamma[c]   * rsqrtf(var[c]   + EPS);
  float sc1 = gamma[c+1] * rsqrtf(var[c+1] + EPS);
  float d0 = sc0*(b0[c]   - mean[c])   + beta[c];
  float d1 = sc1*(b0[c+1] - mean[c+1]) + beta[c+1];
  float2 wv[D_IN];
  #pragma unroll
  for (int k=0;k<D_IN;k++) wv[k] = *(const float2*)(W0 + k*H + c);
  #pragma unroll
  for (int i=0;i<8;i++){
    int nl = w*8 + i;
    float a0 = 0.0f, a1 = 0.0f;
    #pragma unroll
    for (int k=0;k<D_IN;k++){
      float xv = xs[nl][k];
      a0 = fmaf(xv, wv[k].x, a0); a1 = fmaf(xv, wv[k].y, a1);
    }
    float r0 = fmaxf(fmaf(sc0, a0, d0), 0.0f);
    float r1 = fmaxf(fmaf(sc1, a1, d1), 0.0f);
    *(unsigned*)(out + (nb + nl)*H + c) = pk_bf16(r0, r1);
  }
}

// ---------------- bf16 MFMA GEMM: C[M,128] = A_bf16[M,128] @ B (+bias) ----------------
__global__ __launch_bounds__(256) void k_gemm_mfma(const unsigned short* __restrict__ A,
      const float* __restrict__ Bsrc, const float* __restrict__ bias, void* __restrict__ Cout,
      int transB, int outMode){
  __shared__ unsigned short Bt[128][136];
  int tid = threadIdx.x;
  long rowBase = (long)blockIdx.x * 128;
  int w = tid >> 6, l = tid & 63;
  int lc = l & 15, q4 = l >> 4;

  if (transB){
    for (int i = tid; i < 4096; i += 256){
      int c = i >> 5, seg = i & 31;
      float4 v = *(const float4*)(Bsrc + (long)c*128 + seg*4);
      uint2 p; p.x = pk_bf16(v.x, v.y); p.y = pk_bf16(v.z, v.w);
      *(uint2*)&Bt[c][seg*4] = p;
    }
  } else {
    for (int i = tid; i < 4096; i += 256){
      int k = i >> 5, seg = i & 31;
      float4 v = *(const float4*)(Bsrc + (long)k*128 + seg*4);
      Bt[seg*4+0][k] = rnd_bf16(v.x); Bt[seg*4+1][k] = rnd_bf16(v.y);
      Bt[seg*4+2][k] = rnd_bf16(v.z); Bt[seg*4+3][k] = rnd_bf16(v.w);
    }
  }

  short8 af[2][4];
  #pragma unroll
  for (int rt=0;rt<2;rt++){
    long row = rowBase + w*32 + rt*16 + lc;
    #pragma unroll
    for (int kc=0;kc<4;kc++)
      af[rt][kc] = *(const short8*)(A + row*128 + kc*32 + q4*8);
  }

  f32x4 acc[2][8];
  #pragma unroll
  for (int rt=0;rt<2;rt++)
    #pragma unroll
    for (int ct=0;ct<8;ct++) acc[rt][ct] = (f32x4){0.f,0.f,0.f,0.f};

  __syncthreads();

  #pragma unroll
  for (int kc=0;kc<4;kc++){
    #pragma unroll
    for (int ct=0;ct<8;ct++){
      short8 bf = *(const short8*)&Bt[ct*16 + lc][kc*32 + q4*8];
      acc[0][ct] = __builtin_amdgcn_mfma_f32_16x16x32_bf16(af[0][kc], bf, acc[0][ct], 0,0,0);
      acc[1][ct] = __builtin_amdgcn_mfma_f32_16x16x32_bf16(af[1][kc], bf, acc[1][ct], 0,0,0);
    }
  }

  float bv[8];
  #pragma unroll
  for (int ct=0;ct<8;ct++) bv[ct] = bias ? bias[ct*16 + lc] : 0.0f;
  #pragma unroll
  for (int rt=0;rt<2;rt++){
    #pragma unroll
    for (int ct=0;ct<8;ct++){
      int col = ct*16 + lc;
      float vv[4];
      #pragma unroll
      for (int i=0;i<4;i++) vv[i] = acc[rt][ct][i] + bv[ct];
      long row0 = rowBase + w*32 + rt*16 + q4*4;
      if (outMode == 0){
        #pragma unroll
        for (int i=0;i<4;i++) ((unsigned short*)Cout)[(row0+i)*128 + col] = rnd_bf16(vv[i]);
      } else {
        #pragma unroll
        for (int i=0;i<4;i++) ((float*)Cout)[(row0+i)*128 + col] = vv[i];
      }
    }
  }
}

// ---------------- fused K+V projection GEMM, writing fragment-major directly ----------------
__global__ __launch_bounds__(256) void k_kv(const unsigned short* __restrict__ A,
      const float* __restrict__ inW, const float* __restrict__ inb,
      unsigned short* __restrict__ FK, unsigned short* __restrict__ FV){
  __shared__ unsigned short Bt[128][136];
  int tid = threadIdx.x;
  int blk = blockIdx.x;
  int isK = (blk < 4);
  const float* Bsrc = inW + (isK ? 128*128 : 256*128);
  const float* bias = inb + (isK ? 128 : 256);
  long rowBase = (long)(blk & 3) * 128;
  int w = tid >> 6, l = tid & 63;
  int lc = l & 15, q4 = l >> 4;

  for (int i = tid; i < 4096; i += 256){
    int c = i >> 5, seg = i & 31;
    float4 v = *(const float4*)(Bsrc + (long)c*128 + seg*4);
    uint2 p; p.x = pk_bf16(v.x, v.y); p.y = pk_bf16(v.z, v.w);
    *(uint2*)&Bt[c][seg*4] = p;
  }

  short8 af[2][4];
  #pragma unroll
  for (int rt=0;rt<2;rt++){
    long row = rowBase + w*32 + rt*16 + lc;
    #pragma unroll
    for (int kc=0;kc<4;kc++)
      af[rt][kc] = *(const short8*)(A + row*128 + kc*32 + q4*8);
  }

  f32x4 acc[2][8];
  #pragma unroll
  for (int rt=0;rt<2;rt++)
    #pragma unroll
    for (int ct=0;ct<8;ct++) acc[rt][ct] = (f32x4){0.f,0.f,0.f,0.f};

  __syncthreads();

  #pragma unroll
  for (int kc=0;kc<4;kc++){
    #pragma unroll
    for (int ct=0;ct<8;ct++){
      short8 bf = *(const short8*)&Bt[ct*16 + lc][kc*32 + q4*8];
      acc[0][ct] = __builtin_amdgcn_mfma_f32_16x16x32_bf16(af[0][kc], bf, acc[0][ct], 0,0,0);
      acc[1][ct] = __builtin_amdgcn_mfma_f32_16x16x32_bf16(af[1][kc], bf, acc[1][ct], 0,0,0);
    }
  }

  float bv[8];
  #pragma unroll
  for (int ct=0;ct<8;ct++) bv[ct] = bias[ct*16 + lc];
  #pragma unroll
  for (int rt=0;rt<2;rt++){
    long rc = ((blk & 3)*128 + w*32 + rt*16) >> 4;
    #pragma unroll
    for (int ct=0;ct<8;ct++){
      float vv[4];
      #pragma unroll
      for (int i=0;i<4;i++) vv[i] = acc[rt][ct][i] + bv[ct];
      int h = ct >> 1;
      if (isK){
        int q4d = (ct*2 + (lc >> 3)) & 3;
        long base = (long)h*16384 + rc*512 + q4d*128 + (q4*4)*8 + (lc & 7);
        #pragma unroll
        for (int i=0;i<4;i++) FK[base + i*8] = rnd_bf16(vv[i]);
      } else {
        long base = (long)h*16384 + rc*512 + q4*128 + lc*8 + (ct & 1)*4;
        us4 p = { rnd_bf16(vv[0]), rnd_bf16(vv[1]), rnd_bf16(vv[2]), rnd_bf16(vv[3]) };
        *(us4*)(FV + base) = p;
      }
    }
  }
}

// ---------------- GCN aggregation + bias + BN + ReLU (layers 1/2), 8-deep unroll ----------------
__global__ __launch_bounds__(256) void k_agg(const unsigned short* __restrict__ m, const int* __restrict__ csr_off,
      const int2* __restrict__ csr_ev, const float* __restrict__ dinv,
      const float* __restrict__ b, const float* __restrict__ gamma, const float* __restrict__ beta,
      const float* __restrict__ mean, const float* __restrict__ var, unsigned short* __restrict__ out){
  int gt = blockIdx.x*256 + threadIdx.x;
  int li = gt & 15;
  int n = gt >> 4;
  int c = li*8;
  float dn = dinv[n], sn = dn*dn;
  float a[8];
  {
    uint4v u = *(const uint4v*)(m + (long)n*H + c);
    a[0]=bflo(u.x)*sn; a[1]=bfhi(u.x)*sn; a[2]=bflo(u.y)*sn; a[3]=bfhi(u.y)*sn;
    a[4]=bflo(u.z)*sn; a[5]=bfhi(u.z)*sn; a[6]=bflo(u.w)*sn; a[7]=bfhi(u.w)*sn;
  }
  int e0 = csr_off[n], e1 = csr_off[n+1];
  int e = e0;
  for (; e + 8 <= e1; e += 8){
    int2 p0 = csr_ev[e],   p1 = csr_ev[e+1], p2 = csr_ev[e+2], p3 = csr_ev[e+3];
    int2 p4 = csr_ev[e+4], p5 = csr_ev[e+5], p6 = csr_ev[e+6], p7 = csr_ev[e+7];
    uint4v u0 = *(const uint4v*)(m + (long)p0.x*H + c);
    uint4v u1 = *(const uint4v*)(m + (long)p1.x*H + c);
    uint4v u2 = *(const uint4v*)(m + (long)p2.x*H + c);
    uint4v u3 = *(const uint4v*)(m + (long)p3.x*H + c);
    uint4v u4 = *(const uint4v*)(m + (long)p4.x*H + c);
    uint4v u5 = *(const uint4v*)(m + (long)p5.x*H + c);
    uint4v u6 = *(const uint4v*)(m + (long)p6.x*H + c);
    uint4v u7 = *(const uint4v*)(m + (long)p7.x*H + c);
    acc8(a, u0, __builtin_bit_cast(float, p0.y));
    acc8(a, u1, __builtin_bit_cast(float, p1.y));
    acc8(a, u2, __builtin_bit_cast(float, p2.y));
    acc8(a, u3, __builtin_bit_cast(float, p3.y));
    acc8(a, u4, __builtin_bit_cast(float, p4.y));
    acc8(a, u5, __builtin_bit_cast(float, p5.y));
    acc8(a, u6, __builtin_bit_cast(float, p6.y));
    acc8(a, u7, __builtin_bit_cast(float, p7.y));
  }
  for (; e + 4 <= e1; e += 4){
    int2 p0 = csr_ev[e], p1 = csr_ev[e+1], p2 = csr_ev[e+2], p3 = csr_ev[e+3];
    uint4v u0 = *(const uint4v*)(m + (long)p0.x*H + c);
    uint4v u1 = *(const uint4v*)(m + (long)p1.x*H + c);
    uint4v u2 = *(const uint4v*)(m + (long)p2.x*H + c);
    uint4v u3 = *(const uint4v*)(m + (long)p3.x*H + c);
    acc8(a, u0, __builtin_bit_cast(float, p0.y));
    acc8(a, u1, __builtin_bit_cast(float, p1.y));
    acc8(a, u2, __builtin_bit_cast(float, p2.y));
    acc8(a, u3, __builtin_bit_cast(float, p3.y));
  }
  for (; e < e1; e++){
    int2 p0 = csr_ev[e];
    uint4v u0 = *(const uint4v*)(m + (long)p0.x*H + c);
    acc8(a, u0, __builtin_bit_cast(float, p0.y));
  }
  float4 g0 = *(const float4*)(gamma + c), g1 = *(const float4*)(gamma + c + 4);
  float4 v0 = *(const float4*)(var   + c), v1 = *(const float4*)(var   + c + 4);
  float4 b0 = *(const float4*)(b     + c), b1 = *(const float4*)(b     + c + 4);
  float4 m0 = *(const float4*)(mean  + c), m1 = *(const float4*)(mean  + c + 4);
  float4 t0 = *(const float4*)(beta  + c), t1 = *(const float4*)(beta  + c + 4);
  float r[8];
  r[0]=fmaxf(g0.x*rsqrtf(v0.x+EPS)*(a[0]+b0.x-m0.x)+t0.x, 0.f);
  r[1]=fmaxf(g0.y*rsqrtf(v0.y+EPS)*(a[1]+b0.y-m0.y)+t0.y, 0.f);
  r[2]=fmaxf(g0.z*rsqrtf(v0.z+EPS)*(a[2]+b0.z-m0.z)+t0.z, 0.f);
  r[3]=fmaxf(g0.w*rsqrtf(v0.w+EPS)*(a[3]+b0.w-m0.w)+t0.w, 0.f);
  r[4]=fmaxf(g1.x*rsqrtf(v1.x+EPS)*(a[4]+b1.x-m1.x)+t1.x, 0.f);
  r[5]=fmaxf(g1.y*rsqrtf(v1.y+EPS)*(a[5]+b1.y-m1.y)+t1.y, 0.f);
  r[6]=fmaxf(g1.z*rsqrtf(v1.z+EPS)*(a[6]+b1.z-m1.z)+t1.z, 0.f);
  r[7]=fmaxf(g1.w*rsqrtf(v1.w+EPS)*(a[7]+b1.w-m1.w)+t1.w, 0.f);
  uint4v p;
  p.x = pk_bf16(r[0],r[1]); p.y = pk_bf16(r[2],r[3]);
  p.z = pk_bf16(r[4],r[5]); p.w = pk_bf16(r[6],r[7]);
  *(uint4v*)(out + (long)n*H + c) = p;
}

// ---------------- fp32 GEMM (res projection, K=25), bf16 out ----------------
__global__ __launch_bounds__(256,2) void k_gemm(const float* __restrict__ A, const float* __restrict__ B,
      const float* __restrict__ bias, void* __restrict__ C, int K, int transB, int outBf16){
  __shared__ float Bs[128][132];
  __shared__ float As[16][128];
  int tid = threadIdx.x;
  long rowBase = (long)blockIdx.x * 128;

  if (!transB){
    for (int idx = tid; idx < 128*128; idx += 256){
      int k = idx >> 7, c = idx & 127;
      Bs[k][c] = (k < K) ? B[(long)k*128 + c] : 0.0f;
    }
  } else {
    for (int idx = tid; idx < 128*128; idx += 256){
      int c = idx >> 7, k = idx & 127;
      Bs[k][c] = (k < K) ? B[(long)c*K + k] : 0.0f;
    }
  }

  float acc[8][8];
  #pragma unroll
  for (int i=0;i<8;i++)
    #pragma unroll
    for (int j=0;j<8;j++) acc[i][j] = 0.0f;

  int rg = tid >> 4, cg = tid & 15;
  int r0 = rg*8, c0 = cg*8;
  int srow = tid >> 1, skoff = (tid & 1)*8;
  const bool fast = ((K & 15) == 0);

  for (int k0 = 0; k0 < K; k0 += 16){
    __syncthreads();
    const float* ap = A + (rowBase + srow)*K + k0 + skoff;
    if (fast){
      float4 v0 = *(const float4*)(ap);
      float4 v1 = *(const float4*)(ap + 4);
      As[skoff+0][srow] = v0.x; As[skoff+1][srow] = v0.y;
      As[skoff+2][srow] = v0.z; As[skoff+3][srow] = v0.w;
      As[skoff+4][srow] = v1.x; As[skoff+5][srow] = v1.y;
      As[skoff+6][srow] = v1.z; As[skoff+7][srow] = v1.w;
    } else {
      #pragma unroll
      for (int j=0;j<8;j++){
        int kk = k0 + skoff + j;
        As[skoff+j][srow] = (kk < K) ? ap[j] : 0.0f;
      }
    }
    __syncthreads();
    #pragma unroll
    for (int k=0;k<16;k++){
      float4 a0 = *(const float4*)(&As[k][r0]);
      float4 a1 = *(const float4*)(&As[k][r0+4]);
      float4 b0 = *(const float4*)(&Bs[k0+k][c0]);
      float4 b1 = *(const float4*)(&Bs[k0+k][c0+4]);
      float a[8] = {a0.x,a0.y,a0.z,a0.w,a1.x,a1.y,a1.z,a1.w};
      float b[8] = {b0.x,b0.y,b0.z,b0.w,b1.x,b1.y,b1.z,b1.w};
      #pragma unroll
      for (int i=0;i<8;i++)
        #pragma unroll
        for (int j=0;j<8;j++)
          acc[i][j] = fmaf(a[i], b[j], acc[i][j]);
    }
  }

  #pragma unroll
  for (int i=0;i<8;i++){
    float o[8];
    #pragma unroll
    for (int j=0;j<8;j++) o[j] = acc[i][j] + (bias ? bias[c0+j] : 0.0f);
    long row = rowBase + r0 + i;
    if (outBf16){
      uint4v p;
      p.x = pk_bf16(o[0],o[1]); p.y = pk_bf16(o[2],o[3]);
      p.z = pk_bf16(o[4],o[5]); p.w = pk_bf16(o[6],o[7]);
      *(uint4v*)((unsigned short*)C + row*128 + c0) = p;
    } else {
      float* cp = (float*)C + row*128 + c0;
      *(float4*)cp = (float4){o[0],o[1],o[2],o[3]};
      *(float4*)(cp+4) = (float4){o[4],o[5],o[6],o[7]};
    }
  }
}

// ---------------- fused q-proj + flash cross-attention, shape-mixed MFMA (R13 config) ----------------
__global__ __launch_bounds__(256,4) void k_attn(const unsigned short* __restrict__ hb,
      const float* __restrict__ inW, const float* __restrict__ inb,
      const unsigned short* __restrict__ Kf, const unsigned short* __restrict__ Vf,
      unsigned short* __restrict__ obuf){
  int tid = threadIdx.x;
  int h = blockIdx.y;
  int w = tid >> 6, l = tid & 63;
  int lc = l & 15, q4 = l >> 4;
  long nb = (long)blockIdx.x*256 + w*64;
  const float scale = 0.25503489f;   // log2(e)/sqrt(32)

  int srcA = lc + (q4 & 1)*32;
  int srcB = srcA + 16;
  bool hi = (q4 >> 1) != 0;

  short8 wq[2][4];
  #pragma unroll
  for (int t=0;t<2;t++){
    #pragma unroll
    for (int kc=0;kc<4;kc++){
      const float* wp = inW + (long)(h*32 + t*16 + lc)*128 + kc*32 + q4*8;
      float4 x0 = *(const float4*)wp;
      float4 x1 = *(const float4*)(wp+4);
      uint4v p; p.x = pk_bf16(x0.x,x0.y); p.y = pk_bf16(x0.z,x0.w);
      p.z = pk_bf16(x1.x,x1.y); p.w = pk_bf16(x1.z,x1.w);
      wq[t][kc] = __builtin_bit_cast(short8, p);
    }
  }
  float bq0[4], bq1[4];
  #pragma unroll
  for (int i=0;i<4;i++){ bq0[i] = inb[h*32 + q4*4 + i]; bq1[i] = inb[h*32 + 16 + q4*4 + i]; }

  short8 qB[4];
  #pragma unroll
  for (int nt=0;nt<4;nt++){
    short8 hf[4];
    #pragma unroll
    for (int kc=0;kc<4;kc++)
      hf[kc] = *(const short8*)(hb + (nb + nt*16 + lc)*128 + kc*32 + q4*8);
    f32x4 qa0 = (f32x4){0.f,0.f,0.f,0.f};
    f32x4 qa1 = (f32x4){0.f,0.f,0.f,0.f};
    #pragma unroll
    for (int kc=0;kc<4;kc++){
      qa0 = __builtin_amdgcn_mfma_f32_16x16x32_bf16(wq[0][kc], hf[kc], qa0, 0,0,0);
      qa1 = __builtin_amdgcn_mfma_f32_16x16x32_bf16(wq[1][kc], hf[kc], qa1, 0,0,0);
    }
    unsigned P0 = pk_bf16((qa0[0]+bq0[0])*scale, (qa0[1]+bq0[1])*scale);
    unsigned P1 = pk_bf16((qa0[2]+bq0[2])*scale, (qa0[3]+bq0[3])*scale);
    unsigned P2 = pk_bf16((qa1[0]+bq1[0])*scale, (qa1[1]+bq1[1])*scale);
    unsigned P3 = pk_bf16((qa1[2]+bq1[2])*scale, (qa1[3]+bq1[3])*scale);
    unsigned x0 = __shfl(P0, srcA), x1 = __shfl(P1, srcA), x2 = __shfl(P2, srcA), x3 = __shfl(P3, srcA);
    unsigned y0 = __shfl(P0, srcB), y1 = __shfl(P1, srcB), y2 = __shfl(P2, srcB), y3 = __shfl(P3, srcB);
    uint4v bp; bp.x = hi?x2:x0; bp.y = hi?x3:x1; bp.z = hi?y2:y0; bp.w = hi?y3:y1;
    qB[nt] = __builtin_bit_cast(short8, bp);
  }

  const short4v ones4 = {(short)0x3F80,(short)0x3F80,(short)0x3F80,(short)0x3F80};
  f32x4 oA[4], oB[4], os[4];
  #pragma unroll
  for (int nt=0;nt<4;nt++){
    oA[nt] = (f32x4){0.f,0.f,0.f,0.f};
    oB[nt] = (f32x4){0.f,0.f,0.f,0.f};
    os[nt] = (f32x4){0.f,0.f,0.f,0.f};
  }

  const unsigned short* Kp = Kf + (long)h*16384 + (long)l*8;
  const unsigned short* Vp = Vf + (long)h*16384 + (long)l*8;

  for (int rc = 0; rc < 32; rc++){
    short8 kf = *(const short8*)(Kp + rc*512);
    uint4v vv = *(const uint4v*)(Vp + rc*512);
    uint2v va = {vv.x, vv.y}, vb = {vv.z, vv.w};
    short4v vfA = __builtin_bit_cast(short4v, va);
    short4v vfB = __builtin_bit_cast(short4v, vb);
    #pragma unroll
    for (int nt=0;nt<4;nt++){
      f32x4 z = {0.f,0.f,0.f,0.f};
      f32x4 s = __builtin_amdgcn_mfma_f32_16x16x32_bf16(kf, qB[nt], z, 0,0,0);
      float e0 = EXP2F(s[0]), e1 = EXP2F(s[1]), e2 = EXP2F(s[2]), e3 = EXP2F(s[3]);
      uint2v pk2; pk2.x = pk_bf16(e0, e1); pk2.y = pk_bf16(e2, e3);
      short4v pf = __builtin_bit_cast(short4v, pk2);
      oA[nt] = mfma_k16(vfA,   pf, oA[nt]);
      oB[nt] = mfma_k16(vfB,   pf, oB[nt]);
      os[nt] = mfma_k16(ones4, pf, os[nt]);
    }
  }

  #pragma unroll
  for (int nt=0;nt<4;nt++){
    float inv = RCPF(os[nt][0]);
    long node = nb + nt*16 + lc;
    us4 a = { rnd_bf16(oA[nt][0]*inv), rnd_bf16(oA[nt][1]*inv),
              rnd_bf16(oA[nt][2]*inv), rnd_bf16(oA[nt][3]*inv) };
    us4 b = { rnd_bf16(oB[nt][0]*inv), rnd_bf16(oB[nt][1]*inv),
              rnd_bf16(oB[nt][2]*inv), rnd_bf16(oB[nt][3]*inv) };
    *(us4*)(obuf + node*128 + h*32 + q4*4) = a;
    *(us4*)(obuf + node*128 + h*32 + 16 + q4*4) = b;
  }
}

// ---------------- fused out-proj + mean-pool + classifier: block = 128 nodes = 2 graphs ----------------
__global__ __launch_bounds__(256) void k_gemm_out(const unsigned short* __restrict__ A,
      const float* __restrict__ Bsrc, const float* __restrict__ bias,
      const float* __restrict__ W1, const float* __restrict__ b1,
      const float* __restrict__ W2, const float* __restrict__ b2, float* __restrict__ out){
  __shared__ unsigned short Bt[128][136];
  __shared__ float pools[4][128];
  __shared__ float pooled[2][128];
  int tid = threadIdx.x;
  long rowBase = (long)blockIdx.x * 128;
  int w = tid >> 6, l = tid & 63;
  int lc = l & 15, q4 = l >> 4;

  for (int i = tid; i < 4096; i += 256){
    int c = i >> 5, seg = i & 31;
    float4 v = *(const float4*)(Bsrc + (long)c*128 + seg*4);
    uint2 p; p.x = pk_bf16(v.x, v.y); p.y = pk_bf16(v.z, v.w);
    *(uint2*)&Bt[c][seg*4] = p;
  }

  short8 af[2][4];
  #pragma unroll
  for (int rt=0;rt<2;rt++){
    long row = rowBase + w*32 + rt*16 + lc;
    #pragma unroll
    for (int kc=0;kc<4;kc++)
      af[rt][kc] = *(const short8*)(A + row*128 + kc*32 + q4*8);
  }

  f32x4 acc[2][8];
  #pragma unroll
  for (int rt=0;rt<2;rt++)
    #pragma unroll
    for (int ct=0;ct<8;ct++) acc[rt][ct] = (f32x4){0.f,0.f,0.f,0.f};

  __syncthreads();

  #pragma unroll
  for (int kc=0;kc<4;kc++){
    #pragma unroll
    for (int ct=0;ct<8;ct++){
      short8 bf = *(const short8*)&Bt[ct*16 + lc][kc*32 + q4*8];
      acc[0][ct] = __builtin_amdgcn_mfma_f32_16x16x32_bf16(af[0][kc], bf, acc[0][ct], 0,0,0);
      acc[1][ct] = __builtin_amdgcn_mfma_f32_16x16x32_bf16(af[1][kc], bf, acc[1][ct], 0,0,0);
    }
  }

  #pragma unroll
  for (int ct=0;ct<8;ct++){
    float ps = acc[0][ct][0]+acc[0][ct][1]+acc[0][ct][2]+acc[0][ct][3]
             + acc[1][ct][0]+acc[1][ct][1]+acc[1][ct][2]+acc[1][ct][3];
    ps += __shfl_xor(ps, 16);
    ps += __shfl_xor(ps, 32);
    if (q4 == 0) pools[w][ct*16 + lc] = ps;
  }
  __syncthreads();

  if (tid < 128){
    int c = tid;
    pooled[0][c] = (pools[0][c] + pools[1][c]) * (1.0f/64.0f) + bias[c];
    pooled[1][c] = (pools[2][c] + pools[3][c]) * (1.0f/64.0f) + bias[c];
  }
  __syncthreads();

  if (tid < 128){
    int g = tid >> 6, tp = tid & 63;
    float hh = b1[tp];
    for (int c=0;c<128;c++) hh = fmaf(pooled[g][c], W1[c*64 + tp], hh);
    hh = fmaxf(hh, 0.0f);
    float v = hh * W2[tp];
    #pragma unroll
    for (int off=32; off>0; off>>=1) v += __shfl_down(v, off);
    if (tp == 0) out[blockIdx.x*2 + g] = v + b2[0];
  }
}

extern "C" void kernel_launch(void* const* d_in, const int* in_sizes, int n_in,
                              void* d_out, int out_size, void* d_ws, size_t ws_size,
                              hipStream_t stream){
  const float* x     = (const float*)d_in[0];
  const int*   ei    = (const int*)d_in[1];
  const float* perres= (const float*)d_in[3];
  const float* W0 = (const float*)d_in[4];
  const float* b0 = (const float*)d_in[5];
  const float* W1 = (const float*)d_in[6];  const float* b1 = (const float*)d_in[7];
  const float* W2 = (const float*)d_in[8];  const float* b2 = (const float*)d_in[9];
  const float* bng = (const float*)d_in[10]; const float* bnb = (const float*)d_in[11];
  const float* bnm = (const float*)d_in[12]; const float* bnv = (const float*)d_in[13];
  const float* resW = (const float*)d_in[14]; const float* resb = (const float*)d_in[15];
  const float* inW  = (const float*)d_in[16]; const float* inb  = (const float*)d_in[17];
  const float* outW = (const float*)d_in[18]; const float* outb = (const float*)d_in[19];
  const float* cW1 = (const float*)d_in[20]; const float* cb1 = (const float*)d_in[21];
  const float* cW2 = (const float*)d_in[22]; const float* cb2 = (const float*)d_in[23];
  float* out = (float*)d_out;

  char* ws = (char*)d_ws;
  size_t off = 0;
  auto alloc = [&](size_t bytes) -> char* {
    char* p = ws + off;
    off += (bytes + 255) & ~(size_t)255;
    return p;
  };
  float* dinv    = (float*)alloc((size_t)N_NODES*4);
  int*   cnt     = (int*)  alloc((size_t)N_NODES*4);
  int*   csr_off = (int*)  alloc((size_t)(N_NODES+1)*4);
  int*   rankb   = (int*)  alloc((size_t)N_EDGES*4);
  int2*  csr_ev  = (int2*) alloc((size_t)N_EDGES*8);
  int*   part    = (int*)  alloc((size_t)256*4);
  unsigned short* mb  = (unsigned short*)alloc((size_t)N_NODES*H*2);  // bf16: m / o
  unsigned short* hb  = (unsigned short*)alloc((size_t)N_NODES*H*2);  // bf16: h
  unsigned short* resbuf = (unsigned short*)alloc((size_t)R_RES*H*2); // bf16
  unsigned short* Kfr = (unsigned short*)alloc((size_t)R_RES*H*2);    // K fragment-major
  unsigned short* Vfr = (unsigned short*)alloc((size_t)H*R_RES*2);    // V fragment-major
  if (off > ws_size) return;

  const int* srcI = ei;
  const int* dstI = ei + N_EDGES;

  // CSR build (parallel scan; fill is atomic-free via per-edge rank)
  (void)hipMemsetAsync(cnt, 0, (size_t)N_NODES*4, stream);
  k_count<<<N_EDGES/256, 256, 0, stream>>>(dstI, cnt, rankb, N_EDGES);
  k_part <<<N_NODES/256, 256, 0, stream>>>(cnt, part);
  k_scanp<<<1, 256, 0, stream>>>(part);
  k_apply<<<N_NODES/256, 256, 0, stream>>>(cnt, part, csr_off, dinv);
  k_fill <<<N_EDGES/256, 256, 0, stream>>>(srcI, dstI, rankb, csr_off, dinv, csr_ev, N_EDGES);

  const int NB = N_NODES/128;
  const int AGB = N_NODES/16;
  // GCN layer 0: fused agg(x)+proj+BN+ReLU (agg(x)@W = agg(x@W))
  k_l0<<<N_NODES/32, 256, 0, stream>>>(x, csr_off, csr_ev, dinv, W0, b0, bng, bnb, bnm, bnv, hb);
  // layers 1/2 via MFMA GEMM + gather-agg
  k_gemm_mfma<<<NB, 256, 0, stream>>>(hb, W1, nullptr, mb, 0, 0);
  k_agg<<<AGB, 256, 0, stream>>>(mb, csr_off, csr_ev, dinv, b1, bng+128, bnb+128, bnm+128, bnv+128, hb);
  k_gemm_mfma<<<NB, 256, 0, stream>>>(hb, W2, nullptr, mb, 0, 0);
  k_agg<<<AGB, 256, 0, stream>>>(mb, csr_off, csr_ev, dinv, b2, bng+256, bnb+256, bnm+256, bnv+256, hb);

  // residue chain: res-proj (K=25), then fused K+V projection writing fragment-major directly
  k_gemm<<<R_RES/128, 256, 0, stream>>>(perres, resW, resb, resbuf, 25, 0, 1);
  k_kv<<<8, 256, 0, stream>>>(resbuf, inW, inb, Kfr, Vfr);

  // fused q-proj + attention (o -> mb)
  dim3 agrid(N_NODES/256, NH);
  k_attn<<<agrid, 256, 0, stream>>>(hb, inW, inb, Kfr, Vfr, mb);

  // fused out-proj + mean pool + classifier
  k_gemm_out<<<NB, 256, 0, stream>>>(mb, outW, outb, cW1, cb1, cW2, cb2, out);
}

// Round 18
// 331.509 us; speedup vs baseline: 1.2819x; 1.0224x over previous
//
#include <hip/hip_runtime.h>
#include <math.h>

#define N_NODES 65536
#define N_EDGES 524288
#define N_GRAPHS 1024
#define H 128
#define R_RES 512
#define NH 4
#define HD 32
#define D_IN 7
#define EPS 1e-5f

typedef __attribute__((ext_vector_type(8))) short short8;
typedef __attribute__((ext_vector_type(4))) short short4v;
typedef __attribute__((ext_vector_type(4))) float f32x4;
typedef __attribute__((ext_vector_type(4))) unsigned uint4v;
typedef __attribute__((ext_vector_type(2))) unsigned uint2v;
typedef __attribute__((ext_vector_type(4))) unsigned short us4;

#if __has_builtin(__builtin_amdgcn_exp2f)
#define EXP2F __builtin_amdgcn_exp2f
#else
#define EXP2F exp2f
#endif
#if __has_builtin(__builtin_amdgcn_rcpf)
#define RCPF __builtin_amdgcn_rcpf
#else
#define RCPF(x) (1.0f/(x))
#endif

// K=16 bf16 MFMA (builtin only visible in device pass)
__device__ __forceinline__ f32x4 mfma_k16(short4v a, short4v b, f32x4 c){
#if defined(__HIP_DEVICE_COMPILE__)
  return __builtin_amdgcn_mfma_f32_16x16x16bf16_1k(a, b, c, 0, 0, 0);
#else
  (void)a; (void)b; return c;
#endif
}

__device__ __forceinline__ unsigned short rnd_bf16(float f){
  return (unsigned short)((__builtin_bit_cast(unsigned, f) + 0x8000u) >> 16);
}
__device__ __forceinline__ unsigned pk_bf16(float lo, float hi){
  unsigned a = __builtin_bit_cast(unsigned, lo) + 0x8000u;
  unsigned b = __builtin_bit_cast(unsigned, hi) + 0x8000u;
  return __builtin_amdgcn_perm(b, a, 0x07060302u);
}
__device__ __forceinline__ float bflo(unsigned u){ return __builtin_bit_cast(float, u << 16); }
__device__ __forceinline__ float bfhi(unsigned u){ return __builtin_bit_cast(float, u & 0xFFFF0000u); }

__device__ __forceinline__ void acc8(float* a, uint4v u, float wgt){
  a[0]=fmaf(bflo(u.x),wgt,a[0]); a[1]=fmaf(bfhi(u.x),wgt,a[1]);
  a[2]=fmaf(bflo(u.y),wgt,a[2]); a[3]=fmaf(bfhi(u.y),wgt,a[3]);
  a[4]=fmaf(bflo(u.z),wgt,a[4]); a[5]=fmaf(bfhi(u.z),wgt,a[5]);
  a[6]=fmaf(bflo(u.w),wgt,a[6]); a[7]=fmaf(bfhi(u.w),wgt,a[7]);
}

// ---------------- CSR build ----------------
__global__ __launch_bounds__(256) void k_count(const int* __restrict__ dst, int* __restrict__ cnt,
                                               int* __restrict__ rank, int E){
  int e = blockIdx.x*256 + threadIdx.x;
  if (e < E) rank[e] = atomicAdd(&cnt[dst[e]], 1);
}

__global__ __launch_bounds__(256) void k_part(const int* __restrict__ cnt, int* __restrict__ part){
  int i = blockIdx.x*256 + threadIdx.x;
  int v = cnt[i];
  #pragma unroll
  for (int off=1; off<64; off<<=1) v += __shfl_xor(v, off);
  __shared__ int red[4];
  if ((threadIdx.x & 63) == 0) red[threadIdx.x >> 6] = v;
  __syncthreads();
  if (threadIdx.x == 0) part[blockIdx.x] = red[0]+red[1]+red[2]+red[3];
}

// scan of part[] folded in (each block scans the 256 partials redundantly)
__global__ __launch_bounds__(256) void k_apply(const int* __restrict__ cnt, const int* __restrict__ part,
      int* __restrict__ csr_off, float* __restrict__ dinv){
  __shared__ int s[256];
  int b = blockIdx.x, t = threadIdx.x;
  int pv = part[t];
  s[t] = pv;
  __syncthreads();
  for (int off=1; off<256; off<<=1){
    int u = (t >= off) ? s[t-off] : 0;
    __syncthreads();
    s[t] += u;
    __syncthreads();
  }
  int base = (b > 0) ? s[b-1] : 0;      // exclusive prefix of chunk sums
  __syncthreads();
  int i = b*256 + t;
  int c = cnt[i];
  s[t] = c;
  __syncthreads();
  for (int off=1; off<256; off<<=1){
    int u = (t >= off) ? s[t-off] : 0;
    __syncthreads();
    s[t] += u;
    __syncthreads();
  }
  int o0 = base + s[t] - c;
  csr_off[i] = o0;
  dinv[i] = rsqrtf(1.0f + (float)c);
  if (i == N_NODES-1) csr_off[N_NODES] = N_EDGES;
}

__global__ __launch_bounds__(256) void k_fill(const int* __restrict__ src, const int* __restrict__ dst,
      const int* __restrict__ rank, const int* __restrict__ csr_off, const float* __restrict__ dinv,
      int2* __restrict__ csr_ev, int E){
  int e = blockIdx.x*256 + threadIdx.x;
  if (e >= E) return;
  int s = src[e], d = dst[e];
  int p = csr_off[d] + rank[e];
  int2 rec;
  rec.x = s;
  rec.y = __builtin_bit_cast(int, dinv[s]*dinv[d]);
  csr_ev[p] = rec;
}

// ---------------- fused layer-0: agg(x) (7 cols) + projection + BN + ReLU ----------------
__global__ __launch_bounds__(256) void k_l0(const float* __restrict__ x, const int* __restrict__ csr_off,
      const int2* __restrict__ csr_ev, const float* __restrict__ dinv,
      const float* __restrict__ W0, const float* __restrict__ b0,
      const float* __restrict__ gamma, const float* __restrict__ beta,
      const float* __restrict__ mean, const float* __restrict__ var,
      unsigned short* __restrict__ out){
  __shared__ float xs[32][8];
  int t = threadIdx.x;
  long nb = (long)blockIdx.x*32;
  {
    int nl = t >> 3, col = t & 7;
    int n = (int)nb + nl;
    int cc = (col < D_IN) ? col : 0;
    float dn = dinv[n];
    float a = x[(long)n*D_IN + cc]*(dn*dn);
    int e0 = csr_off[n], e1 = csr_off[n+1];
    int e = e0;
    for (; e + 2 <= e1; e += 2){
      int2 p0 = csr_ev[e], p1 = csr_ev[e+1];
      a = fmaf(x[(long)p0.x*D_IN + cc], __builtin_bit_cast(float, p0.y), a);
      a = fmaf(x[(long)p1.x*D_IN + cc], __builtin_bit_cast(float, p1.y), a);
    }
    if (e < e1){
      int2 p0 = csr_ev[e];
      a = fmaf(x[(long)p0.x*D_IN + cc], __builtin_bit_cast(float, p0.y), a);
    }
    xs[nl][col] = a;
  }
  __syncthreads();
  int w = t >> 6, l = t & 63;
  int c = 2*l;
  float sc0 = gamma[c]   * rsqrtf(var[c]   + EPS);
  float sc1 = gamma[c+1] * rsqrtf(var[c+1] + EPS);
  float d0 = sc0*(b0[c]   - mean[c])   + beta[c];
  float d1 = sc1*(b0[c+1] - mean[c+1]) + beta[c+1];
  float2 wv[D_IN];
  #pragma unroll
  for (int k=0;k<D_IN;k++) wv[k] = *(const float2*)(W0 + k*H + c);
  #pragma unroll
  for (int i=0;i<8;i++){
    int nl = w*8 + i;
    float a0 = 0.0f, a1 = 0.0f;
    #pragma unroll
    for (int k=0;k<D_IN;k++){
      float xv = xs[nl][k];
      a0 = fmaf(xv, wv[k].x, a0); a1 = fmaf(xv, wv[k].y, a1);
    }
    float r0 = fmaxf(fmaf(sc0, a0, d0), 0.0f);
    float r1 = fmaxf(fmaf(sc1, a1, d1), 0.0f);
    *(unsigned*)(out + (nb + nl)*H + c) = pk_bf16(r0, r1);
  }
}

// ---------------- bf16 MFMA GEMM: C[M,128] = A_bf16[M,128] @ B (+bias) ----------------
__global__ __launch_bounds__(256) void k_gemm_mfma(const unsigned short* __restrict__ A,
      const float* __restrict__ Bsrc, const float* __restrict__ bias, void* __restrict__ Cout,
      int transB, int outMode){
  __shared__ unsigned short Bt[128][136];
  int tid = threadIdx.x;
  long rowBase = (long)blockIdx.x * 128;
  int w = tid >> 6, l = tid & 63;
  int lc = l & 15, q4 = l >> 4;

  if (transB){
    for (int i = tid; i < 4096; i += 256){
      int c = i >> 5, seg = i & 31;
      float4 v = *(const float4*)(Bsrc + (long)c*128 + seg*4);
      uint2 p; p.x = pk_bf16(v.x, v.y); p.y = pk_bf16(v.z, v.w);
      *(uint2*)&Bt[c][seg*4] = p;
    }
  } else {
    for (int i = tid; i < 4096; i += 256){
      int k = i >> 5, seg = i & 31;
      float4 v = *(const float4*)(Bsrc + (long)k*128 + seg*4);
      Bt[seg*4+0][k] = rnd_bf16(v.x); Bt[seg*4+1][k] = rnd_bf16(v.y);
      Bt[seg*4+2][k] = rnd_bf16(v.z); Bt[seg*4+3][k] = rnd_bf16(v.w);
    }
  }

  short8 af[2][4];
  #pragma unroll
  for (int rt=0;rt<2;rt++){
    long row = rowBase + w*32 + rt*16 + lc;
    #pragma unroll
    for (int kc=0;kc<4;kc++)
      af[rt][kc] = *(const short8*)(A + row*128 + kc*32 + q4*8);
  }

  f32x4 acc[2][8];
  #pragma unroll
  for (int rt=0;rt<2;rt++)
    #pragma unroll
    for (int ct=0;ct<8;ct++) acc[rt][ct] = (f32x4){0.f,0.f,0.f,0.f};

  __syncthreads();

  #pragma unroll
  for (int kc=0;kc<4;kc++){
    #pragma unroll
    for (int ct=0;ct<8;ct++){
      short8 bf = *(const short8*)&Bt[ct*16 + lc][kc*32 + q4*8];
      acc[0][ct] = __builtin_amdgcn_mfma_f32_16x16x32_bf16(af[0][kc], bf, acc[0][ct], 0,0,0);
      acc[1][ct] = __builtin_amdgcn_mfma_f32_16x16x32_bf16(af[1][kc], bf, acc[1][ct], 0,0,0);
    }
  }

  float bv[8];
  #pragma unroll
  for (int ct=0;ct<8;ct++) bv[ct] = bias ? bias[ct*16 + lc] : 0.0f;
  #pragma unroll
  for (int rt=0;rt<2;rt++){
    #pragma unroll
    for (int ct=0;ct<8;ct++){
      int col = ct*16 + lc;
      float vv[4];
      #pragma unroll
      for (int i=0;i<4;i++) vv[i] = acc[rt][ct][i] + bv[ct];
      long row0 = rowBase + w*32 + rt*16 + q4*4;
      if (outMode == 0){
        #pragma unroll
        for (int i=0;i<4;i++) ((unsigned short*)Cout)[(row0+i)*128 + col] = rnd_bf16(vv[i]);
      } else {
        #pragma unroll
        for (int i=0;i<4;i++) ((float*)Cout)[(row0+i)*128 + col] = vv[i];
      }
    }
  }
}

// ---------------- fused res-proj + K/V projection, writing fragment-major directly ----------------
// Grid = 8 blocks: b<4 -> K rows (b&3)*128.., b>=4 -> V. Each block computes its own 128-row
// resbuf tile in LDS (fp32 math, same accumulation order as the old k_gemm -> bit-identical).
// LDS: [0,12800) perres tile | [12800,27136) resW^T pad-28 | [27136,59904) resC bf16 |
//      [59904,60416) resb. Bt (34816B) overlays [0,..) after A-frags are in registers.
__global__ __launch_bounds__(256) void k_kv(const float* __restrict__ perres,
      const float* __restrict__ resW, const float* __restrict__ resb,
      const float* __restrict__ inW, const float* __restrict__ inb,
      unsigned short* __restrict__ FK, unsigned short* __restrict__ FV){
  __shared__ __align__(16) char smem[60416];
  float* prA = (float*)smem;                       // [128][25]
  float* wT  = (float*)(smem + 12800);             // [128][28] (c-major, padded)
  unsigned short* resC = (unsigned short*)(smem + 27136);  // [128][128] bf16
  float* rbl = (float*)(smem + 59904);             // [128] bias
  int tid = threadIdx.x;
  int blk = blockIdx.x;
  int isK = (blk < 4);
  const float* Bsrc = inW + (isK ? 128*128 : 256*128);
  const float* bias = inb + (isK ? 128 : 256);
  long rowBase = (long)(blk & 3) * 128;
  int w = tid >> 6, l = tid & 63;
  int lc = l & 15, q4 = l >> 4;

  // phase 1: stage perres tile (contiguous), resW^T, resb
  for (int i = tid; i < 3200; i += 256) prA[i] = perres[rowBase*25 + i];
  for (int i = tid; i < 3200; i += 256){
    int k = i >> 7, c = i & 127;
    wT[c*28 + k] = resW[i];
  }
  if (tid < 128) rbl[tid] = resb[tid];
  __syncthreads();

  // phase 2: resC[r][c] = sum_k prA[r][k]*wT[c][k] + resb[c]  (fp32, k ascending)
  {
    int r = tid >> 1, c0 = (tid & 1)*64;
    float a[25];
    #pragma unroll
    for (int k=0;k<25;k++) a[k] = prA[r*25 + k];
    for (int c = c0; c < c0+64; c += 2){
      float acc0 = rbl[c], acc1 = rbl[c+1];
      const float* w0p = wT + c*28;
      const float* w1p = w0p + 28;
      #pragma unroll
      for (int k=0;k<25;k++){
        acc0 = fmaf(a[k], w0p[k], acc0);
        acc1 = fmaf(a[k], w1p[k], acc1);
      }
      *(unsigned*)&resC[r*128 + c] = pk_bf16(acc0, acc1);
    }
  }
  __syncthreads();

  // phase 3: A-fragments from LDS resC
  short8 af[2][4];
  #pragma unroll
  for (int rt=0;rt<2;rt++){
    int row = w*32 + rt*16 + lc;
    #pragma unroll
    for (int kc=0;kc<4;kc++)
      af[rt][kc] = *(const short8*)&resC[row*128 + kc*32 + q4*8];
  }
  __syncthreads();

  // phase 4: stage Bt (overlays smem base; resC region partly reused)
  unsigned short (*Bt)[136] = (unsigned short(*)[136])smem;
  for (int i = tid; i < 4096; i += 256){
    int c = i >> 5, seg = i & 31;
    float4 v = *(const float4*)(Bsrc + (long)c*128 + seg*4);
    uint2 p; p.x = pk_bf16(v.x, v.y); p.y = pk_bf16(v.z, v.w);
    *(uint2*)&Bt[c][seg*4] = p;
  }

  f32x4 acc[2][8];
  #pragma unroll
  for (int rt=0;rt<2;rt++)
    #pragma unroll
    for (int ct=0;ct<8;ct++) acc[rt][ct] = (f32x4){0.f,0.f,0.f,0.f};

  __syncthreads();

  #pragma unroll
  for (int kc=0;kc<4;kc++){
    #pragma unroll
    for (int ct=0;ct<8;ct++){
      short8 bf = *(const short8*)&Bt[ct*16 + lc][kc*32 + q4*8];
      acc[0][ct] = __builtin_amdgcn_mfma_f32_16x16x32_bf16(af[0][kc], bf, acc[0][ct], 0,0,0);
      acc[1][ct] = __builtin_amdgcn_mfma_f32_16x16x32_bf16(af[1][kc], bf, acc[1][ct], 0,0,0);
    }
  }

  float bv[8];
  #pragma unroll
  for (int ct=0;ct<8;ct++) bv[ct] = bias[ct*16 + lc];
  #pragma unroll
  for (int rt=0;rt<2;rt++){
    long rc = ((blk & 3)*128 + w*32 + rt*16) >> 4;
    #pragma unroll
    for (int ct=0;ct<8;ct++){
      float vv[4];
      #pragma unroll
      for (int i=0;i<4;i++) vv[i] = acc[rt][ct][i] + bv[ct];
      int h = ct >> 1;
      if (isK){
        int q4d = (ct*2 + (lc >> 3)) & 3;
        long base = (long)h*16384 + rc*512 + q4d*128 + (q4*4)*8 + (lc & 7);
        #pragma unroll
        for (int i=0;i<4;i++) FK[base + i*8] = rnd_bf16(vv[i]);
      } else {
        long base = (long)h*16384 + rc*512 + q4*128 + lc*8 + (ct & 1)*4;
        us4 p = { rnd_bf16(vv[0]), rnd_bf16(vv[1]), rnd_bf16(vv[2]), rnd_bf16(vv[3]) };
        *(us4*)(FV + base) = p;
      }
    }
  }
}

// ---------------- GCN aggregation + bias + BN + ReLU (layers 1/2), 8-deep unroll ----------------
__global__ __launch_bounds__(256) void k_agg(const unsigned short* __restrict__ m, const int* __restrict__ csr_off,
      const int2* __restrict__ csr_ev, const float* __restrict__ dinv,
      const float* __restrict__ b, const float* __restrict__ gamma, const float* __restrict__ beta,
      const float* __restrict__ mean, const float* __restrict__ var, unsigned short* __restrict__ out){
  int gt = blockIdx.x*256 + threadIdx.x;
  int li = gt & 15;
  int n = gt >> 4;
  int c = li*8;
  float dn = dinv[n], sn = dn*dn;
  float a[8];
  {
    uint4v u = *(const uint4v*)(m + (long)n*H + c);
    a[0]=bflo(u.x)*sn; a[1]=bfhi(u.x)*sn; a[2]=bflo(u.y)*sn; a[3]=bfhi(u.y)*sn;
    a[4]=bflo(u.z)*sn; a[5]=bfhi(u.z)*sn; a[6]=bflo(u.w)*sn; a[7]=bfhi(u.w)*sn;
  }
  int e0 = csr_off[n], e1 = csr_off[n+1];
  int e = e0;
  for (; e + 8 <= e1; e += 8){
    int2 p0 = csr_ev[e],   p1 = csr_ev[e+1], p2 = csr_ev[e+2], p3 = csr_ev[e+3];
    int2 p4 = csr_ev[e+4], p5 = csr_ev[e+5], p6 = csr_ev[e+6], p7 = csr_ev[e+7];
    uint4v u0 = *(const uint4v*)(m + (long)p0.x*H + c);
    uint4v u1 = *(const uint4v*)(m + (long)p1.x*H + c);
    uint4v u2 = *(const uint4v*)(m + (long)p2.x*H + c);
    uint4v u3 = *(const uint4v*)(m + (long)p3.x*H + c);
    uint4v u4 = *(const uint4v*)(m + (long)p4.x*H + c);
    uint4v u5 = *(const uint4v*)(m + (long)p5.x*H + c);
    uint4v u6 = *(const uint4v*)(m + (long)p6.x*H + c);
    uint4v u7 = *(const uint4v*)(m + (long)p7.x*H + c);
    acc8(a, u0, __builtin_bit_cast(float, p0.y));
    acc8(a, u1, __builtin_bit_cast(float, p1.y));
    acc8(a, u2, __builtin_bit_cast(float, p2.y));
    acc8(a, u3, __builtin_bit_cast(float, p3.y));
    acc8(a, u4, __builtin_bit_cast(float, p4.y));
    acc8(a, u5, __builtin_bit_cast(float, p5.y));
    acc8(a, u6, __builtin_bit_cast(float, p6.y));
    acc8(a, u7, __builtin_bit_cast(float, p7.y));
  }
  for (; e + 4 <= e1; e += 4){
    int2 p0 = csr_ev[e], p1 = csr_ev[e+1], p2 = csr_ev[e+2], p3 = csr_ev[e+3];
    uint4v u0 = *(const uint4v*)(m + (long)p0.x*H + c);
    uint4v u1 = *(const uint4v*)(m + (long)p1.x*H + c);
    uint4v u2 = *(const uint4v*)(m + (long)p2.x*H + c);
    uint4v u3 = *(const uint4v*)(m + (long)p3.x*H + c);
    acc8(a, u0, __builtin_bit_cast(float, p0.y));
    acc8(a, u1, __builtin_bit_cast(float, p1.y));
    acc8(a, u2, __builtin_bit_cast(float, p2.y));
    acc8(a, u3, __builtin_bit_cast(float, p3.y));
  }
  for (; e < e1; e++){
    int2 p0 = csr_ev[e];
    uint4v u0 = *(const uint4v*)(m + (long)p0.x*H + c);
    acc8(a, u0, __builtin_bit_cast(float, p0.y));
  }
  float4 g0 = *(const float4*)(gamma + c), g1 = *(const float4*)(gamma + c + 4);
  float4 v0 = *(const float4*)(var   + c), v1 = *(const float4*)(var   + c + 4);
  float4 b0 = *(const float4*)(b     + c), b1 = *(const float4*)(b     + c + 4);
  float4 m0 = *(const float4*)(mean  + c), m1 = *(const float4*)(mean  + c + 4);
  float4 t0 = *(const float4*)(beta  + c), t1 = *(const float4*)(beta  + c + 4);
  float r[8];
  r[0]=fmaxf(g0.x*rsqrtf(v0.x+EPS)*(a[0]+b0.x-m0.x)+t0.x, 0.f);
  r[1]=fmaxf(g0.y*rsqrtf(v0.y+EPS)*(a[1]+b0.y-m0.y)+t0.y, 0.f);
  r[2]=fmaxf(g0.z*rsqrtf(v0.z+EPS)*(a[2]+b0.z-m0.z)+t0.z, 0.f);
  r[3]=fmaxf(g0.w*rsqrtf(v0.w+EPS)*(a[3]+b0.w-m0.w)+t0.w, 0.f);
  r[4]=fmaxf(g1.x*rsqrtf(v1.x+EPS)*(a[4]+b1.x-m1.x)+t1.x, 0.f);
  r[5]=fmaxf(g1.y*rsqrtf(v1.y+EPS)*(a[5]+b1.y-m1.y)+t1.y, 0.f);
  r[6]=fmaxf(g1.z*rsqrtf(v1.z+EPS)*(a[6]+b1.z-m1.z)+t1.z, 0.f);
  r[7]=fmaxf(g1.w*rsqrtf(v1.w+EPS)*(a[7]+b1.w-m1.w)+t1.w, 0.f);
  uint4v p;
  p.x = pk_bf16(r[0],r[1]); p.y = pk_bf16(r[2],r[3]);
  p.z = pk_bf16(r[4],r[5]); p.w = pk_bf16(r[6],r[7]);
  *(uint4v*)(out + (long)n*H + c) = p;
}

// ---------------- fused q-proj + flash cross-attention, shape-mixed MFMA (R13 config) ----------------
__global__ __launch_bounds__(256,4) void k_attn(const unsigned short* __restrict__ hb,
      const float* __restrict__ inW, const float* __restrict__ inb,
      const unsigned short* __restrict__ Kf, const unsigned short* __restrict__ Vf,
      unsigned short* __restrict__ obuf){
  int tid = threadIdx.x;
  int h = blockIdx.y;
  int w = tid >> 6, l = tid & 63;
  int lc = l & 15, q4 = l >> 4;
  long nb = (long)blockIdx.x*256 + w*64;
  const float scale = 0.25503489f;   // log2(e)/sqrt(32)

  int srcA = lc + (q4 & 1)*32;
  int srcB = srcA + 16;
  bool hi = (q4 >> 1) != 0;

  short8 wq[2][4];
  #pragma unroll
  for (int t=0;t<2;t++){
    #pragma unroll
    for (int kc=0;kc<4;kc++){
      const float* wp = inW + (long)(h*32 + t*16 + lc)*128 + kc*32 + q4*8;
      float4 x0 = *(const float4*)wp;
      float4 x1 = *(const float4*)(wp+4);
      uint4v p; p.x = pk_bf16(x0.x,x0.y); p.y = pk_bf16(x0.z,x0.w);
      p.z = pk_bf16(x1.x,x1.y); p.w = pk_bf16(x1.z,x1.w);
      wq[t][kc] = __builtin_bit_cast(short8, p);
    }
  }
  float bq0[4], bq1[4];
  #pragma unroll
  for (int i=0;i<4;i++){ bq0[i] = inb[h*32 + q4*4 + i]; bq1[i] = inb[h*32 + 16 + q4*4 + i]; }

  short8 qB[4];
  #pragma unroll
  for (int nt=0;nt<4;nt++){
    short8 hf[4];
    #pragma unroll
    for (int kc=0;kc<4;kc++)
      hf[kc] = *(const short8*)(hb + (nb + nt*16 + lc)*128 + kc*32 + q4*8);
    f32x4 qa0 = (f32x4){0.f,0.f,0.f,0.f};
    f32x4 qa1 = (f32x4){0.f,0.f,0.f,0.f};
    #pragma unroll
    for (int kc=0;kc<4;kc++){
      qa0 = __builtin_amdgcn_mfma_f32_16x16x32_bf16(wq[0][kc], hf[kc], qa0, 0,0,0);
      qa1 = __builtin_amdgcn_mfma_f32_16x16x32_bf16(wq[1][kc], hf[kc], qa1, 0,0,0);
    }
    unsigned P0 = pk_bf16((qa0[0]+bq0[0])*scale, (qa0[1]+bq0[1])*scale);
    unsigned P1 = pk_bf16((qa0[2]+bq0[2])*scale, (qa0[3]+bq0[3])*scale);
    unsigned P2 = pk_bf16((qa1[0]+bq1[0])*scale, (qa1[1]+bq1[1])*scale);
    unsigned P3 = pk_bf16((qa1[2]+bq1[2])*scale, (qa1[3]+bq1[3])*scale);
    unsigned x0 = __shfl(P0, srcA), x1 = __shfl(P1, srcA), x2 = __shfl(P2, srcA), x3 = __shfl(P3, srcA);
    unsigned y0 = __shfl(P0, srcB), y1 = __shfl(P1, srcB), y2 = __shfl(P2, srcB), y3 = __shfl(P3, srcB);
    uint4v bp; bp.x = hi?x2:x0; bp.y = hi?x3:x1; bp.z = hi?y2:y0; bp.w = hi?y3:y1;
    qB[nt] = __builtin_bit_cast(short8, bp);
  }

  const short4v ones4 = {(short)0x3F80,(short)0x3F80,(short)0x3F80,(short)0x3F80};
  f32x4 oA[4], oB[4], os[4];
  #pragma unroll
  for (int nt=0;nt<4;nt++){
    oA[nt] = (f32x4){0.f,0.f,0.f,0.f};
    oB[nt] = (f32x4){0.f,0.f,0.f,0.f};
    os[nt] = (f32x4){0.f,0.f,0.f,0.f};
  }

  const unsigned short* Kp = Kf + (long)h*16384 + (long)l*8;
  const unsigned short* Vp = Vf + (long)h*16384 + (long)l*8;

  for (int rc = 0; rc < 32; rc++){
    short8 kf = *(const short8*)(Kp + rc*512);
    uint4v vv = *(const uint4v*)(Vp + rc*512);
    uint2v va = {vv.x, vv.y}, vb = {vv.z, vv.w};
    short4v vfA = __builtin_bit_cast(short4v, va);
    short4v vfB = __builtin_bit_cast(short4v, vb);
    #pragma unroll
    for (int nt=0;nt<4;nt++){
      f32x4 z = {0.f,0.f,0.f,0.f};
      f32x4 s = __builtin_amdgcn_mfma_f32_16x16x32_bf16(kf, qB[nt], z, 0,0,0);
      float e0 = EXP2F(s[0]), e1 = EXP2F(s[1]), e2 = EXP2F(s[2]), e3 = EXP2F(s[3]);
      uint2v pk2; pk2.x = pk_bf16(e0, e1); pk2.y = pk_bf16(e2, e3);
      short4v pf = __builtin_bit_cast(short4v, pk2);
      oA[nt] = mfma_k16(vfA,   pf, oA[nt]);
      oB[nt] = mfma_k16(vfB,   pf, oB[nt]);
      os[nt] = mfma_k16(ones4, pf, os[nt]);
    }
  }

  #pragma unroll
  for (int nt=0;nt<4;nt++){
    float inv = RCPF(os[nt][0]);
    long node = nb + nt*16 + lc;
    us4 a = { rnd_bf16(oA[nt][0]*inv), rnd_bf16(oA[nt][1]*inv),
              rnd_bf16(oA[nt][2]*inv), rnd_bf16(oA[nt][3]*inv) };
    us4 b = { rnd_bf16(oB[nt][0]*inv), rnd_bf16(oB[nt][1]*inv),
              rnd_bf16(oB[nt][2]*inv), rnd_bf16(oB[nt][3]*inv) };
    *(us4*)(obuf + node*128 + h*32 + q4*4) = a;
    *(us4*)(obuf + node*128 + h*32 + 16 + q4*4) = b;
  }
}

// ---------------- fused out-proj + mean-pool + classifier: block = 128 nodes = 2 graphs ----------------
__global__ __launch_bounds__(256) void k_gemm_out(const unsigned short* __restrict__ A,
      const float* __restrict__ Bsrc, const float* __restrict__ bias,
      const float* __restrict__ W1, const float* __restrict__ b1,
      const float* __restrict__ W2, const float* __restrict__ b2, float* __restrict__ out){
  __shared__ unsigned short Bt[128][136];
  __shared__ float pools[4][128];
  __shared__ float pooled[2][128];
  int tid = threadIdx.x;
  long rowBase = (long)blockIdx.x * 128;
  int w = tid >> 6, l = tid & 63;
  int lc = l & 15, q4 = l >> 4;

  for (int i = tid; i < 4096; i += 256){
    int c = i >> 5, seg = i & 31;
    float4 v = *(const float4*)(Bsrc + (long)c*128 + seg*4);
    uint2 p; p.x = pk_bf16(v.x, v.y); p.y = pk_bf16(v.z, v.w);
    *(uint2*)&Bt[c][seg*4] = p;
  }

  short8 af[2][4];
  #pragma unroll
  for (int rt=0;rt<2;rt++){
    long row = rowBase + w*32 + rt*16 + lc;
    #pragma unroll
    for (int kc=0;kc<4;kc++)
      af[rt][kc] = *(const short8*)(A + row*128 + kc*32 + q4*8);
  }

  f32x4 acc[2][8];
  #pragma unroll
  for (int rt=0;rt<2;rt++)
    #pragma unroll
    for (int ct=0;ct<8;ct++) acc[rt][ct] = (f32x4){0.f,0.f,0.f,0.f};

  __syncthreads();

  #pragma unroll
  for (int kc=0;kc<4;kc++){
    #pragma unroll
    for (int ct=0;ct<8;ct++){
      short8 bf = *(const short8*)&Bt[ct*16 + lc][kc*32 + q4*8];
      acc[0][ct] = __builtin_amdgcn_mfma_f32_16x16x32_bf16(af[0][kc], bf, acc[0][ct], 0,0,0);
      acc[1][ct] = __builtin_amdgcn_mfma_f32_16x16x32_bf16(af[1][kc], bf, acc[1][ct], 0,0,0);
    }
  }

  #pragma unroll
  for (int ct=0;ct<8;ct++){
    float ps = acc[0][ct][0]+acc[0][ct][1]+acc[0][ct][2]+acc[0][ct][3]
             + acc[1][ct][0]+acc[1][ct][1]+acc[1][ct][2]+acc[1][ct][3];
    ps += __shfl_xor(ps, 16);
    ps += __shfl_xor(ps, 32);
    if (q4 == 0) pools[w][ct*16 + lc] = ps;
  }
  __syncthreads();

  if (tid < 128){
    int c = tid;
    pooled[0][c] = (pools[0][c] + pools[1][c]) * (1.0f/64.0f) + bias[c];
    pooled[1][c] = (pools[2][c] + pools[3][c]) * (1.0f/64.0f) + bias[c];
  }
  __syncthreads();

  if (tid < 128){
    int g = tid >> 6, tp = tid & 63;
    float hh = b1[tp];
    for (int c=0;c<128;c++) hh = fmaf(pooled[g][c], W1[c*64 + tp], hh);
    hh = fmaxf(hh, 0.0f);
    float v = hh * W2[tp];
    #pragma unroll
    for (int off=32; off>0; off>>=1) v += __shfl_down(v, off);
    if (tp == 0) out[blockIdx.x*2 + g] = v + b2[0];
  }
}

extern "C" void kernel_launch(void* const* d_in, const int* in_sizes, int n_in,
                              void* d_out, int out_size, void* d_ws, size_t ws_size,
                              hipStream_t stream){
  const float* x     = (const float*)d_in[0];
  const int*   ei    = (const int*)d_in[1];
  const float* perres= (const float*)d_in[3];
  const float* W0 = (const float*)d_in[4];
  const float* b0 = (const float*)d_in[5];
  const float* W1 = (const float*)d_in[6];  const float* b1 = (const float*)d_in[7];
  const float* W2 = (const float*)d_in[8];  const float* b2 = (const float*)d_in[9];
  const float* bng = (const float*)d_in[10]; const float* bnb = (const float*)d_in[11];
  const float* bnm = (const float*)d_in[12]; const float* bnv = (const float*)d_in[13];
  const float* resW = (const float*)d_in[14]; const float* resb = (const float*)d_in[15];
  const float* inW  = (const float*)d_in[16]; const float* inb  = (const float*)d_in[17];
  const float* outW = (const float*)d_in[18]; const float* outb = (const float*)d_in[19];
  const float* cW1 = (const float*)d_in[20]; const float* cb1 = (const float*)d_in[21];
  const float* cW2 = (const float*)d_in[22]; const float* cb2 = (const float*)d_in[23];
  float* out = (float*)d_out;

  char* ws = (char*)d_ws;
  size_t off = 0;
  auto alloc = [&](size_t bytes) -> char* {
    char* p = ws + off;
    off += (bytes + 255) & ~(size_t)255;
    return p;
  };
  float* dinv    = (float*)alloc((size_t)N_NODES*4);
  int*   cnt     = (int*)  alloc((size_t)N_NODES*4);
  int*   csr_off = (int*)  alloc((size_t)(N_NODES+1)*4);
  int*   rankb   = (int*)  alloc((size_t)N_EDGES*4);
  int2*  csr_ev  = (int2*) alloc((size_t)N_EDGES*8);
  int*   part    = (int*)  alloc((size_t)256*4);
  unsigned short* mb  = (unsigned short*)alloc((size_t)N_NODES*H*2);  // bf16: m / o
  unsigned short* hb  = (unsigned short*)alloc((size_t)N_NODES*H*2);  // bf16: h
  unsigned short* Kfr = (unsigned short*)alloc((size_t)R_RES*H*2);    // K fragment-major
  unsigned short* Vfr = (unsigned short*)alloc((size_t)H*R_RES*2);    // V fragment-major
  if (off > ws_size) return;

  const int* srcI = ei;
  const int* dstI = ei + N_EDGES;

  // CSR build (scan folded into apply; fill atomic-free via rank)
  (void)hipMemsetAsync(cnt, 0, (size_t)N_NODES*4, stream);
  k_count<<<N_EDGES/256, 256, 0, stream>>>(dstI, cnt, rankb, N_EDGES);
  k_part <<<N_NODES/256, 256, 0, stream>>>(cnt, part);
  k_apply<<<N_NODES/256, 256, 0, stream>>>(cnt, part, csr_off, dinv);
  k_fill <<<N_EDGES/256, 256, 0, stream>>>(srcI, dstI, rankb, csr_off, dinv, csr_ev, N_EDGES);

  const int NB = N_NODES/128;
  const int AGB = N_NODES/16;
  // GCN layer 0: fused agg(x)+proj+BN+ReLU
  k_l0<<<N_NODES/32, 256, 0, stream>>>(x, csr_off, csr_ev, dinv, W0, b0, bng, bnb, bnm, bnv, hb);
  // layers 1/2 via MFMA GEMM + gather-agg
  k_gemm_mfma<<<NB, 256, 0, stream>>>(hb, W1, nullptr, mb, 0, 0);
  k_agg<<<AGB, 256, 0, stream>>>(mb, csr_off, csr_ev, dinv, b1, bng+128, bnb+128, bnm+128, bnv+128, hb);
  k_gemm_mfma<<<NB, 256, 0, stream>>>(hb, W2, nullptr, mb, 0, 0);
  k_agg<<<AGB, 256, 0, stream>>>(mb, csr_off, csr_ev, dinv, b2, bng+256, bnb+256, bnm+256, bnv+256, hb);

  // fused res-proj + K/V projection writing fragment-major directly
  k_kv<<<8, 256, 0, stream>>>(perres, resW, resb, inW, inb, Kfr, Vfr);

  // fused q-proj + attention (o -> mb)
  dim3 agrid(N_NODES/256, NH);
  k_attn<<<agrid, 256, 0, stream>>>(hb, inW, inb, Kfr, Vfr, mb);

  // fused out-proj + mean pool + classifier
  k_gemm_out<<<NB, 256, 0, stream>>>(mb, outW, outb, cW1, cb1, cW2, cb2, out);
}